// Round 5
// baseline (5714.090 us; speedup 1.0000x reference)
//
#include <hip/hip_runtime.h>
#include <hip/hip_bf16.h>
#include <math.h>

#define B_ 2
#define K_ 2
#define NN_ 4096
#define T_ 8
#define C_ 3
#define H_ 192
#define S_ 1638
#define KK_ 16
#define E_ (S_*KK_)          // 26208
#define NROW (B_*K_*S_)      // 6552
#define EROW (B_*K_*E_)      // 104832
#define SHARP_ 5.0f

typedef __hip_bfloat16 bf;

__device__ int   g_isbf16;
__device__ int   g_viol;
__device__ __align__(16) float g_var[B_*NN_];
__device__ __align__(16) float g_soft[B_*NN_];
__device__ __align__(16) float g_accum[B_*2];
__device__ __align__(16) int   g_topidx[B_*S_];
__device__ __align__(16) float g_possel[B_*S_*3];
__device__ __align__(16) float g_masksel[B_*S_];
__device__ __align__(16) float g_x0[NROW*10];
__device__ __align__(16) int   g_knn[B_*E_];
__device__ __align__(16) float g_ea[B_*E_*4];
__device__ __align__(16) int   g_indeg[B_*S_];
__device__ __align__(16) int   g_cursor[B_*S_];
__device__ __align__(16) int   g_off[B_*(S_+1)];
__device__ __align__(16) int   g_list[B_*E_];
__device__ __align__(16) float g_PQ[(size_t)NROW*384];
__device__ __align__(16) float g_h[(size_t)NROW*H_];
__device__ __align__(16) float g_hhf[(size_t)NROW*H_];
__device__ __align__(16) float g_tf[(size_t)NROW*H_];
__device__ __align__(16) float g_m1f[(size_t)EROW*H_];
__device__ __align__(16) float g_m2f[(size_t)EROW*H_];

__device__ __forceinline__ float LD(const void* p, long i){
  return g_isbf16 ? __bfloat162float(((const bf*)p)[i]) : ((const float*)p)[i];
}
__device__ __forceinline__ float gelu_f(float x){ return 0.5f*x*(1.0f + erff(x*0.70710678118654752f)); }

// ---------------- input dtype detect (inputs are O(10); fp32-as-bf16 -> junk) ----------------
__global__ void k_viol(const void* a, const void* b, const void* c){
  int t = threadIdx.x;              // 256 threads
  const bf* pa = (const bf*)a; const bf* pb = (const bf*)b; const bf* pc = (const bf*)c;
  int bad = 0;
  #pragma unroll
  for (int s = 0; s < 2; ++s){
    float va = __bfloat162float(pa[t + s*256]);
    float vb = __bfloat162float(pb[t + s*256]);
    float vc = __bfloat162float(pc[t + s*256]);
    if (!(fabsf(va) <= 1000.f)) bad = 1;
    if (!(fabsf(vb) <= 1000.f)) bad = 1;
    if (!(fabsf(vc) <= 1000.f)) bad = 1;
  }
  if (threadIdx.x == 0) g_viol = 0;
  __syncthreads();
  if (bad) atomicOr(&g_viol, 1);
  __syncthreads();
  if (threadIdx.x == 0) g_isbf16 = (g_viol == 0) ? 1 : 0;
}

__global__ void k_zero(){
  int tid = blockIdx.x*256 + threadIdx.x;
  if (tid < B_*S_){ g_indeg[tid]=0; g_cursor[tid]=0; }
  if (tid < B_*2) g_accum[tid]=0.f;
}

// ---------------- var_pp, np pairwise-8 semantics ----------------
__global__ void k_var(const void* __restrict__ vel){
  int b = blockIdx.y;
  int n = blockIdx.x*256 + threadIdx.x;
  float v = 0.f;
  #pragma unroll
  for (int c = 0; c < 3; ++c){
    float x[8];
    #pragma unroll
    for (int t = 0; t < 8; ++t)
      x[t] = LD(vel, ((long)(b*T_+t)*NN_ + n)*3 + c);
    float m = __fadd_rn(__fadd_rn(__fadd_rn(x[0],x[1]), __fadd_rn(x[2],x[3])),
                        __fadd_rn(__fadd_rn(x[4],x[5]), __fadd_rn(x[6],x[7]))) / 8.0f;
    float d[8];
    #pragma unroll
    for (int t = 0; t < 8; ++t){ float dd = __fadd_rn(x[t], -m); d[t] = __fmul_rn(dd,dd); }
    float sv = __fadd_rn(__fadd_rn(__fadd_rn(d[0],d[1]), __fadd_rn(d[2],d[3])),
                         __fadd_rn(__fadd_rn(d[4],d[5]), __fadd_rn(d[6],d[7])));
    v = __fadd_rn(v, sv / 7.0f);
  }
  g_var[b*NN_ + n] = v;
  float s1 = v, s2 = v*v;
  #pragma unroll
  for (int o = 32; o; o >>= 1){ s1 += __shfl_xor(s1,o,64); s2 += __shfl_xor(s2,o,64); }
  __shared__ float r1[4], r2[4];
  int lane = threadIdx.x & 63, wid = threadIdx.x >> 6;
  if (!lane){ r1[wid]=s1; r2[wid]=s2; }
  __syncthreads();
  if (threadIdx.x == 0){
    atomicAdd(&g_accum[b*2+0], r1[0]+r1[1]+r1[2]+r1[3]);
    atomicAdd(&g_accum[b*2+1], r2[0]+r2[1]+r2[2]+r2[3]);
  }
}

__global__ void k_soft(const void* __restrict__ air){
  int b = blockIdx.y;
  int n = blockIdx.x*256 + threadIdx.x;
  float S1 = g_accum[b*2], S2 = g_accum[b*2+1];
  float mean = S1*(1.f/NN_);
  float sd = sqrtf(fmaxf((S2 - S1*S1*(1.f/NN_))*(1.f/(NN_-1)), 0.f));
  float v = g_var[b*NN_+n];
  float z = (v-mean)/(sd+1e-8f);
  float sig = 1.f/(1.f+expf(-SHARP_*z));
  g_soft[b*NN_+n] = sig*(1.f - LD(air, b*NN_+n));
}

// ---------------- stable rank-based top-S (exact top_k semantics) ----------------
__global__ void k_rank(){
  __shared__ float sv[NN_];
  int b = blockIdx.y;
  for (int t = threadIdx.x; t < NN_; t += 256) sv[t] = g_var[b*NN_+t];
  __syncthreads();
  int i = blockIdx.x*256 + threadIdx.x;
  float vi = sv[i];
  int rank = 0;
  for (int j = 0; j < NN_; ++j){
    float vj = sv[j];
    rank += ((vj > vi) || (vj == vi && j < i)) ? 1 : 0;
  }
  if (rank < S_) g_topidx[b*S_ + rank] = i;
}

__global__ void k_gather(const void* __restrict__ pos, const void* __restrict__ ub,
                         const void* __restrict__ vel){
  int gi = blockIdx.x*256 + threadIdx.x;
  if (gi >= B_*S_) return;
  int b = gi / S_, s = gi - b*S_;
  int node = g_topidx[gi];
  float px = LD(pos, ((long)b*NN_+node)*3+0);
  float py = LD(pos, ((long)b*NN_+node)*3+1);
  float pz = LD(pos, ((long)b*NN_+node)*3+2);
  g_possel[gi*3+0]=px; g_possel[gi*3+1]=py; g_possel[gi*3+2]=pz;
  g_masksel[gi] = g_soft[b*NN_+node];
  float vf = g_var[b*NN_+node];
  float vl0 = LD(vel, ((long)(b*T_+7)*NN_+node)*3+0);
  float vl1 = LD(vel, ((long)(b*T_+7)*NN_+node)*3+1);
  float vl2 = LD(vel, ((long)(b*T_+7)*NN_+node)*3+2);
  for (int k = 0; k < K_; ++k){
    long row = (long)(b*K_+k)*S_ + s;
    float* x = g_x0 + row*10;
    x[0]=LD(ub, ((long)(b*K_+k)*NN_+node)*3+0);
    x[1]=LD(ub, ((long)(b*K_+k)*NN_+node)*3+1);
    x[2]=LD(ub, ((long)(b*K_+k)*NN_+node)*3+2);
    x[3]=vl0; x[4]=vl1; x[5]=vl2;
    x[6]=px;  x[7]=py;  x[8]=pz;
    x[9]=vf;
  }
}

__global__ void k_knn(){
  __shared__ float px[S_], py[S_], pz[S_];
  int b = blockIdx.y;
  int j = blockIdx.x*256 + threadIdx.x;
  for (int t = threadIdx.x; t < S_; t += 256){
    px[t] = g_possel[(b*S_+t)*3+0];
    py[t] = g_possel[(b*S_+t)*3+1];
    pz[t] = g_possel[(b*S_+t)*3+2];
  }
  __syncthreads();
  if (j >= S_) return;
  float xj=px[j], yj=py[j], zj=pz[j];
  float dist[KK_]; int id[KK_];
  #pragma unroll
  for (int t = 0; t < KK_; ++t){ dist[t]=3.0e38f; id[t]=0; }
  float worst = 3.0e38f;
  for (int c = 0; c < S_; ++c){
    if (c == j) continue;
    float dx=__fadd_rn(px[c],-xj), dy=__fadd_rn(py[c],-yj), dz=__fadd_rn(pz[c],-zj);
    float d2 = __fadd_rn(__fadd_rn(__fmul_rn(dx,dx), __fmul_rn(dy,dy)), __fmul_rn(dz,dz));
    if (d2 < worst){
      int p = KK_-1;
      while (p > 0 && dist[p-1] > d2){ dist[p]=dist[p-1]; id[p]=id[p-1]; --p; }
      dist[p]=d2; id[p]=c;
      worst = dist[KK_-1];
    }
  }
  for (int t = 0; t < KK_; ++t){
    int i = id[t];
    g_knn[(b*S_+j)*KK_ + t] = i;
    float rx = __fadd_rn(px[i],-xj), ry = __fadd_rn(py[i],-yj), rz = __fadd_rn(pz[i],-zj);
    float dd = sqrtf(__fadd_rn(__fadd_rn(__fmul_rn(rx,rx), __fmul_rn(ry,ry)), __fmul_rn(rz,rz)));
    float* o = g_ea + ((long)b*E_ + j*KK_ + t)*4;
    o[0]=rx; o[1]=ry; o[2]=rz; o[3]=dd;
    atomicAdd(&g_indeg[b*S_+i], 1);
  }
}

__global__ void k_scan(){
  __shared__ int sA[2048], sB[2048];
  int b = blockIdx.x, tid = threadIdx.x;   // 1024
  for (int i = tid; i < 2048; i += 1024) sA[i] = (i < S_) ? g_indeg[b*S_+i] : 0;
  __syncthreads();
  int *src = sA, *dst = sB;
  for (int d = 1; d < 2048; d <<= 1){
    for (int i = tid; i < 2048; i += 1024) dst[i] = src[i] + (i >= d ? src[i-d] : 0);
    __syncthreads();
    int* t2 = src; src = dst; dst = t2;
  }
  if (tid == 0) g_off[b*(S_+1)] = 0;
  for (int i = tid; i < S_; i += 1024) g_off[b*(S_+1)+i+1] = src[i];
}

__global__ void k_fill(){
  int idx = blockIdx.x*256 + threadIdx.x;
  if (idx >= B_*E_) return;
  int b = idx / E_, e = idx - b*E_;
  int i = g_knn[idx];
  int slot = atomicAdd(&g_cursor[b*S_+i], 1);
  g_list[b*E_ + g_off[b*(S_+1)+i] + slot] = e;
}

// ---------------- conv0 node projection (K=10) ----------------
__global__ void k_proj0(const void* __restrict__ w1){
  int gi = blockIdx.x*256 + threadIdx.x;
  if (gi >= NROW*384) return;
  int row = gi / 384, n = gi - (gi/384)*384;
  const float* x = g_x0 + (size_t)row*10;
  float acc = 0.f;
  if (n < H_){
    #pragma unroll
    for (int f = 0; f < 10; ++f) acc += x[f] * (LD(w1, f*H_+n) - LD(w1, (10+f)*H_+n));
  } else {
    int hc = n - H_;
    #pragma unroll
    for (int f = 0; f < 10; ++f) acc += x[f] * LD(w1, (10+f)*H_+hc);
  }
  g_PQ[(size_t)row*384 + n] = acc;
}

// ---------------- node projection layers 1..9 (VALU fp32) ----------------
__global__ void k_pq(const void* __restrict__ cw1, int m){
  int gi = blockIdx.x*256 + threadIdx.x;
  if (gi >= NROW*384) return;
  int row = gi / 384, n = gi - (gi/384)*384;
  long base = (long)m*388*H_;
  const float* hrow = g_h + (size_t)row*H_;
  float acc = 0.f;
  if (n < H_){
    for (int k = 0; k < H_; ++k)
      acc += hrow[k] * (LD(cw1, base + (long)k*H_ + n) - LD(cw1, base + (long)(H_+k)*H_ + n));
  } else {
    int nc = n - H_;
    for (int k = 0; k < H_; ++k)
      acc += hrow[k] * LD(cw1, base + (long)(H_+k)*H_ + nc);
  }
  g_PQ[(size_t)row*384 + n] = acc;
}

// ---------------- per-edge m1 = gelu(P[i]+Q[j]+ea@w1c+b1) ----------------
__global__ void k_edge(const void* __restrict__ w1cB, long w1cO,
                       const void* __restrict__ b1B, long b1O){
  int row = blockIdx.x;            // EROW
  int col = threadIdx.x;           // 192
  int bk = row / E_, e = row - bk*E_, b = bk >> 1;
  int j = e >> 4;
  int i = g_knn[b*E_ + e];
  float pv = g_PQ[((size_t)(bk*S_ + i))*384 + col];
  float qv = g_PQ[((size_t)(bk*S_ + j))*384 + 192 + col];
  const float* ep = g_ea + ((size_t)b*E_ + e)*4;
  float acc = pv + qv + LD(b1B, b1O + col);
  acc += ep[0]*LD(w1cB, w1cO+col) + ep[1]*LD(w1cB, w1cO+H_+col)
       + ep[2]*LD(w1cB, w1cO+2*H_+col) + ep[3]*LD(w1cB, w1cO+3*H_+col);
  g_m1f[(size_t)row*H_ + col] = gelu_f(acc);
}

// ---------------- VALU GEMM K=192, 8 rows/block ----------------
template<int MODE>
__global__ __launch_bounds__(192) void k_gemmv(const void* __restrict__ wB, long wO,
                                               const void* __restrict__ bB, long bO){
  __shared__ float ins[8][H_];
  const float* in = (MODE == 0) ? g_m1f : g_hhf;
  float* outp     = (MODE == 0) ? g_m2f : g_tf;
  long rowBase = (long)blockIdx.x * 8;
  int col = threadIdx.x;
  #pragma unroll
  for (int r = 0; r < 8; ++r) ins[r][col] = in[(rowBase+r)*H_ + col];
  __syncthreads();
  float acc[8];
  #pragma unroll
  for (int r = 0; r < 8; ++r) acc[r] = 0.f;
  for (int k = 0; k < H_; ++k){
    float w = LD(wB, wO + (long)k*H_ + col);
    #pragma unroll
    for (int r = 0; r < 8; ++r) acc[r] += ins[r][k]*w;
  }
  float bb = LD(bB, bO + col);
  #pragma unroll
  for (int r = 0; r < 8; ++r){
    float v = acc[r] + bb;
    if (MODE == 1) v = gelu_f(v);
    outp[(rowBase+r)*H_ + col] = v;
  }
}

// ---------------- CSR aggregate + LayerNorm (+residual) ----------------
template<int RES>
__global__ void k_aggln(const void* __restrict__ gB, long gO,
                        const void* __restrict__ beB, long beO){
  int row = blockIdx.x;   // NROW
  int col = threadIdx.x;  // 192
  int bk = row / S_, i = row - bk*S_, b = bk >> 1;
  int off = g_off[b*(S_+1)+i];
  int deg = g_off[b*(S_+1)+i+1] - off;
  float acc = 0.f;
  for (int d = 0; d < deg; ++d){
    int e = g_list[b*E_ + off + d];
    acc += g_m2f[((size_t)bk*E_ + e)*H_ + col];
  }
  float s = acc, qq = acc*acc;
  #pragma unroll
  for (int o = 32; o; o >>= 1){ s += __shfl_xor(s,o,64); qq += __shfl_xor(qq,o,64); }
  __shared__ float ws[3][2];
  int wid = col >> 6, lane = col & 63;
  if (!lane){ ws[wid][0]=s; ws[wid][1]=qq; }
  __syncthreads();
  float Sm = ws[0][0]+ws[1][0]+ws[2][0];
  float Qm = ws[0][1]+ws[1][1]+ws[2][1];
  float mu = Sm*(1.f/H_);
  float var = Qm*(1.f/H_) - mu*mu;
  float rstd = rsqrtf(fmaxf(var, 0.f) + 1e-5f);
  float y = (acc-mu)*rstd*LD(gB,gO+col) + LD(beB,beO+col);
  if (RES) y += g_h[(size_t)row*H_ + col];
  g_h[(size_t)row*H_ + col] = y;
}

__global__ void k_lnhead(const void* __restrict__ g, const void* __restrict__ be){
  int row = blockIdx.x;
  int col = threadIdx.x;
  float x = g_h[(size_t)row*H_ + col];
  float s = x, qq = x*x;
  #pragma unroll
  for (int o = 32; o; o >>= 1){ s += __shfl_xor(s,o,64); qq += __shfl_xor(qq,o,64); }
  __shared__ float ws[3][2];
  int wid = col >> 6, lane = col & 63;
  if (!lane){ ws[wid][0]=s; ws[wid][1]=qq; }
  __syncthreads();
  float Sm = ws[0][0]+ws[1][0]+ws[2][0];
  float Qm = ws[0][1]+ws[1][1]+ws[2][1];
  float mu = Sm*(1.f/H_);
  float var = Qm*(1.f/H_) - mu*mu;
  float rstd = rsqrtf(fmaxf(var, 0.f) + 1e-5f);
  g_hhf[(size_t)row*H_ + col] = (x-mu)*rstd*LD(g,col) + LD(be,col);
}

// ---------------- output: FP32 (reference output dtype is float32) ----------------
__global__ void k_initout(const void* __restrict__ ub, const void* __restrict__ air, float* __restrict__ out){
  int gi = blockIdx.x*256 + threadIdx.x;   // 49152
  int n = (gi/3) % NN_;
  int b = gi / (K_*NN_*C_);
  float a = 1.f - LD(air, b*NN_+n);
  out[gi] = LD(ub, gi) * a;
}

__global__ void k_headout(const void* __restrict__ w2, const void* __restrict__ b2,
                          const void* __restrict__ ub, const void* __restrict__ air,
                          float* __restrict__ out){
  int row = blockIdx.x*4 + (threadIdx.x >> 6);
  int lane = threadIdx.x & 63;
  if (row >= NROW) return;
  float t0 = g_tf[(size_t)row*H_ + lane];
  float t1 = g_tf[(size_t)row*H_ + lane + 64];
  float t2 = g_tf[(size_t)row*H_ + lane + 128];
  float d[3];
  #pragma unroll
  for (int c = 0; c < 3; ++c){
    float p = t0*LD(w2,lane*3+c) + t1*LD(w2,(lane+64)*3+c) + t2*LD(w2,(lane+128)*3+c);
    #pragma unroll
    for (int o = 32; o; o >>= 1) p += __shfl_xor(p,o,64);
    d[c] = p + LD(b2,c);
  }
  if (lane == 0){
    int bk = row / S_, s = row - bk*S_, b = bk >> 1;
    float msk = g_masksel[b*S_+s];
    int node = g_topidx[b*S_+s];
    float am = 1.f - LD(air, b*NN_+node);
    #pragma unroll
    for (int c = 0; c < 3; ++c){
      long oi = ((long)bk*NN_ + node)*3 + c;
      out[oi] = (LD(ub,oi) + d[c]*msk)*am;
    }
  }
}

extern "C" void kernel_launch(void* const* d_in, const int* in_sizes, int n_in,
                              void* d_out, int out_size, void* d_ws, size_t ws_size,
                              hipStream_t stream) {
  (void)in_sizes; (void)n_in; (void)d_ws; (void)ws_size; (void)out_size;
  const void* u_base = d_in[0];
  const void* pos    = d_in[1];
  const void* vel    = d_in[2];
  const void* air    = d_in[3];
  const void* c0w1   = d_in[4];
  const void* c0b1   = d_in[5];
  const void* c0w2   = d_in[6];
  const void* c0b2   = d_in[7];
  const void* c0g    = d_in[8];
  const void* c0be   = d_in[9];
  const void* cw1    = d_in[10];
  const void* cb1    = d_in[11];
  const void* cw2    = d_in[12];
  const void* cb2    = d_in[13];
  const void* cg     = d_in[14];
  const void* cbe    = d_in[15];
  const void* hg     = d_in[16];
  const void* hbe    = d_in[17];
  const void* hw1    = d_in[18];
  const void* hb1    = d_in[19];
  const void* hw2    = d_in[20];
  const void* hb2    = d_in[21];
  float* out = (float*)d_out;

  k_viol<<<1, 256, 0, stream>>>(u_base, pos, vel);
  k_zero<<<13, 256, 0, stream>>>();
  k_var<<<dim3(16, B_), 256, 0, stream>>>(vel);
  k_soft<<<dim3(16, B_), 256, 0, stream>>>(air);
  k_rank<<<dim3(16, B_), 256, 0, stream>>>();
  k_gather<<<13, 256, 0, stream>>>(pos, u_base, vel);
  k_knn<<<dim3(7, B_), 256, 0, stream>>>();
  k_scan<<<B_, 1024, 0, stream>>>();
  k_fill<<<205, 256, 0, stream>>>();
  k_initout<<<192, 256, 0, stream>>>(u_base, air, out);
  k_proj0<<<9828, 256, 0, stream>>>(c0w1);

  for (int l = 0; l < 10; ++l){
    if (l > 0) k_pq<<<9828, 256, 0, stream>>>(cw1, l-1);

    long w1cO = (l == 0) ? 20L*H_ : ((long)(l-1)*388 + 384)*H_;
    const void* w1cB = (l == 0) ? c0w1 : cw1;
    long lOff = (l == 0) ? 0 : (long)(l-1)*H_;
    const void* b1B = (l == 0) ? c0b1 : cb1;
    k_edge<<<EROW, 192, 0, stream>>>(w1cB, w1cO, b1B, lOff);

    const void* w2B = (l == 0) ? c0w2 : cw2;
    long w2O = (l == 0) ? 0 : (long)(l-1)*H_*H_;
    const void* b2B = (l == 0) ? c0b2 : cb2;
    k_gemmv<0><<<EROW/8, 192, 0, stream>>>(w2B, w2O, b2B, lOff);

    const void* gB  = (l == 0) ? c0g  : cg;
    const void* beB = (l == 0) ? c0be : cbe;
    if (l > 0) k_aggln<1><<<NROW, 192, 0, stream>>>(gB, lOff, beB, lOff);
    else       k_aggln<0><<<NROW, 192, 0, stream>>>(gB, lOff, beB, lOff);
  }

  k_lnhead<<<NROW, 192, 0, stream>>>(hg, hbe);
  k_gemmv<1><<<NROW/8, 192, 0, stream>>>(hw1, 0, hb1, 0);
  k_headout<<<NROW/4, 256, 0, stream>>>(hw2, hb2, u_base, air, out);
}

// Round 6
// 1362.740 us; speedup vs baseline: 4.1931x; 4.1931x over previous
//
#include <hip/hip_runtime.h>
#include <hip/hip_bf16.h>
#include <math.h>

#define B_ 2
#define K_ 2
#define NN_ 4096
#define T_ 8
#define C_ 3
#define H_ 192
#define S_ 1638
#define KK_ 16
#define E_ (S_*KK_)          // 26208
#define NROW (B_*K_*S_)      // 6552
#define EROW (B_*K_*E_)      // 104832
#define SHARP_ 5.0f

typedef __hip_bfloat16 bf;
typedef unsigned long long ull;
typedef __bf16 bf16x8 __attribute__((ext_vector_type(8)));
typedef float f32x4 __attribute__((ext_vector_type(4)));

__device__ int   g_isbf16;
__device__ int   g_viol;
__device__ __align__(16) float g_var[B_*NN_];
__device__ __align__(16) float g_soft[B_*NN_];
__device__ __align__(16) float g_accum[B_*2];
__device__ __align__(16) int   g_topidx[B_*S_];
__device__ __align__(16) float g_possel[B_*S_*3];
__device__ __align__(16) float g_masksel[B_*S_];
__device__ __align__(16) float g_x0[NROW*10];
__device__ __align__(16) int   g_knn[B_*E_];
__device__ __align__(16) float g_ea[B_*E_*4];
__device__ __align__(16) int   g_indeg[B_*S_];
__device__ __align__(16) int   g_cursor[B_*S_];
__device__ __align__(16) int   g_off[B_*(S_+1)];
__device__ __align__(16) int   g_list[B_*E_];
__device__ __align__(16) float g_PQ[(size_t)NROW*384];
__device__ __align__(16) float g_h[(size_t)NROW*H_];
__device__ __align__(16) bf    g_hbf[(size_t)NROW*H_];
__device__ __align__(16) bf    g_m1[(size_t)EROW*H_];
__device__ __align__(16) bf    g_m2[(size_t)EROW*H_];
__device__ __align__(16) bf    g_hh[(size_t)NROW*H_];
__device__ __align__(16) bf    g_t[(size_t)NROW*H_];
__device__ __align__(16) bf    g_w2p[(size_t)11*H_*H_];
__device__ __align__(16) bf    g_wcp[(size_t)9*H_*384];

__device__ __forceinline__ float bf2f(bf x){ return __bfloat162float(x); }
__device__ __forceinline__ float LD(const void* p, long i){
  return g_isbf16 ? __bfloat162float(((const bf*)p)[i]) : ((const float*)p)[i];
}
__device__ __forceinline__ float gelu_f(float x){ return 0.5f*x*(1.0f + erff(x*0.70710678118654752f)); }
__device__ __forceinline__ ull shfl_xor_u64(ull v, int m){
  unsigned lo = (unsigned)v, hi = (unsigned)(v >> 32);
  lo = __shfl_xor(lo, m, 64); hi = __shfl_xor(hi, m, 64);
  return ((ull)hi << 32) | lo;
}

// ---------------- input dtype detect ----------------
__global__ void k_viol(const void* a, const void* b, const void* c){
  int t = threadIdx.x;
  const bf* pa = (const bf*)a; const bf* pb = (const bf*)b; const bf* pc = (const bf*)c;
  int bad = 0;
  #pragma unroll
  for (int s = 0; s < 2; ++s){
    float va = __bfloat162float(pa[t + s*256]);
    float vb = __bfloat162float(pb[t + s*256]);
    float vc = __bfloat162float(pc[t + s*256]);
    if (!(fabsf(va) <= 1000.f)) bad = 1;
    if (!(fabsf(vb) <= 1000.f)) bad = 1;
    if (!(fabsf(vc) <= 1000.f)) bad = 1;
  }
  if (threadIdx.x == 0) g_viol = 0;
  __syncthreads();
  if (bad) atomicOr(&g_viol, 1);
  __syncthreads();
  if (threadIdx.x == 0) g_isbf16 = (g_viol == 0) ? 1 : 0;
}

__global__ void k_zero(){
  int tid = blockIdx.x*256 + threadIdx.x;
  if (tid < B_*S_){ g_indeg[tid]=0; g_cursor[tid]=0; }
  if (tid < B_*2) g_accum[tid]=0.f;
}

// ---------------- var_pp, np pairwise-8 semantics ----------------
__global__ void k_var(const void* __restrict__ vel){
  int b = blockIdx.y;
  int n = blockIdx.x*256 + threadIdx.x;
  float v = 0.f;
  #pragma unroll
  for (int c = 0; c < 3; ++c){
    float x[8];
    #pragma unroll
    for (int t = 0; t < 8; ++t)
      x[t] = LD(vel, ((long)(b*T_+t)*NN_ + n)*3 + c);
    float m = __fadd_rn(__fadd_rn(__fadd_rn(x[0],x[1]), __fadd_rn(x[2],x[3])),
                        __fadd_rn(__fadd_rn(x[4],x[5]), __fadd_rn(x[6],x[7]))) / 8.0f;
    float d[8];
    #pragma unroll
    for (int t = 0; t < 8; ++t){ float dd = __fadd_rn(x[t], -m); d[t] = __fmul_rn(dd,dd); }
    float sv = __fadd_rn(__fadd_rn(__fadd_rn(d[0],d[1]), __fadd_rn(d[2],d[3])),
                         __fadd_rn(__fadd_rn(d[4],d[5]), __fadd_rn(d[6],d[7])));
    v = __fadd_rn(v, sv / 7.0f);
  }
  g_var[b*NN_ + n] = v;
  float s1 = v, s2 = v*v;
  #pragma unroll
  for (int o = 32; o; o >>= 1){ s1 += __shfl_xor(s1,o,64); s2 += __shfl_xor(s2,o,64); }
  __shared__ float r1[4], r2[4];
  int lane = threadIdx.x & 63, wid = threadIdx.x >> 6;
  if (!lane){ r1[wid]=s1; r2[wid]=s2; }
  __syncthreads();
  if (threadIdx.x == 0){
    atomicAdd(&g_accum[b*2+0], r1[0]+r1[1]+r1[2]+r1[3]);
    atomicAdd(&g_accum[b*2+1], r2[0]+r2[1]+r2[2]+r2[3]);
  }
}

__global__ void k_soft(const void* __restrict__ air){
  int b = blockIdx.y;
  int n = blockIdx.x*256 + threadIdx.x;
  float S1 = g_accum[b*2], S2 = g_accum[b*2+1];
  float mean = S1*(1.f/NN_);
  float sd = sqrtf(fmaxf((S2 - S1*S1*(1.f/NN_))*(1.f/(NN_-1)), 0.f));
  float v = g_var[b*NN_+n];
  float z = (v-mean)/(sd+1e-8f);
  float sig = 1.f/(1.f+expf(-SHARP_*z));
  g_soft[b*NN_+n] = sig*(1.f - LD(air, b*NN_+n));
}

// ---------------- stable rank-based top-S ----------------
__global__ void k_rank(){
  __shared__ float sv[NN_];
  int b = blockIdx.y;
  for (int t = threadIdx.x; t < NN_; t += 256) sv[t] = g_var[b*NN_+t];
  __syncthreads();
  int i = blockIdx.x*256 + threadIdx.x;
  float vi = sv[i];
  int rank = 0;
  for (int j = 0; j < NN_; ++j){
    float vj = sv[j];
    rank += ((vj > vi) || (vj == vi && j < i)) ? 1 : 0;
  }
  if (rank < S_) g_topidx[b*S_ + rank] = i;
}

__global__ void k_gather(const void* __restrict__ pos, const void* __restrict__ ub,
                         const void* __restrict__ vel){
  int gi = blockIdx.x*256 + threadIdx.x;
  if (gi >= B_*S_) return;
  int b = gi / S_, s = gi - b*S_;
  int node = g_topidx[gi];
  float px = LD(pos, ((long)b*NN_+node)*3+0);
  float py = LD(pos, ((long)b*NN_+node)*3+1);
  float pz = LD(pos, ((long)b*NN_+node)*3+2);
  g_possel[gi*3+0]=px; g_possel[gi*3+1]=py; g_possel[gi*3+2]=pz;
  g_masksel[gi] = g_soft[b*NN_+node];
  float vf = g_var[b*NN_+node];
  float vl0 = LD(vel, ((long)(b*T_+7)*NN_+node)*3+0);
  float vl1 = LD(vel, ((long)(b*T_+7)*NN_+node)*3+1);
  float vl2 = LD(vel, ((long)(b*T_+7)*NN_+node)*3+2);
  for (int k = 0; k < K_; ++k){
    long row = (long)(b*K_+k)*S_ + s;
    float* x = g_x0 + row*10;
    x[0]=LD(ub, ((long)(b*K_+k)*NN_+node)*3+0);
    x[1]=LD(ub, ((long)(b*K_+k)*NN_+node)*3+1);
    x[2]=LD(ub, ((long)(b*K_+k)*NN_+node)*3+2);
    x[3]=vl0; x[4]=vl1; x[5]=vl2;
    x[6]=px;  x[7]=py;  x[8]=pz;
    x[9]=vf;
  }
}

// ---------------- KNN: one wave per query node ----------------
__global__ __launch_bounds__(256) void k_knn(){
  __shared__ float px[S_], py[S_], pz[S_];
  int b = blockIdx.y;
  int j = blockIdx.x*4 + (threadIdx.x >> 6);
  int lane = threadIdx.x & 63;
  for (int t = threadIdx.x; t < S_; t += 256){
    px[t] = g_possel[(b*S_+t)*3+0];
    py[t] = g_possel[(b*S_+t)*3+1];
    pz[t] = g_possel[(b*S_+t)*3+2];
  }
  __syncthreads();
  if (j >= S_) return;
  float xj=px[j], yj=py[j], zj=pz[j];
  float dist[KK_]; int id[KK_];
  #pragma unroll
  for (int t = 0; t < KK_; ++t){ dist[t]=3.0e38f; id[t]=0x7fffffff; }
  // lane-local top-16 over candidates lane, lane+64, ...
  for (int c = lane; c < S_; c += 64){
    if (c == j) continue;
    float dx=__fadd_rn(px[c],-xj), dy=__fadd_rn(py[c],-yj), dz=__fadd_rn(pz[c],-zj);
    float d2 = __fadd_rn(__fadd_rn(__fmul_rn(dx,dx), __fmul_rn(dy,dy)), __fmul_rn(dz,dz));
    if (d2 < dist[KK_-1]){
      int p = 0;
      #pragma unroll
      for (int q = 0; q < KK_; ++q) p += (dist[q] <= d2) ? 1 : 0;
      #pragma unroll
      for (int q = KK_-1; q >= 1; --q){
        bool mv = (q > p);
        dist[q] = mv ? dist[q-1] : dist[q];
        id[q]   = mv ? id[q-1]   : id[q];
      }
      #pragma unroll
      for (int q = 0; q < KK_; ++q){ if (q == p){ dist[q] = d2; id[q] = c; } }
    }
  }
  // merge: 16 rounds of wave-argmin on (d2,idx) keys; winner pops front
  ull mykey = 0;
  #pragma unroll
  for (int t = 0; t < KK_; ++t){
    ull k = (((ull)__float_as_uint(dist[0])) << 32) | (unsigned)id[0];
    ull m = k;
    #pragma unroll
    for (int o = 32; o; o >>= 1){ ull other = shfl_xor_u64(m, o); m = (other < m) ? other : m; }
    if (k == m){
      #pragma unroll
      for (int q = 0; q < KK_-1; ++q){ dist[q]=dist[q+1]; id[q]=id[q+1]; }
      dist[KK_-1] = 3.0e38f; id[KK_-1] = 0x7fffffff;
    }
    if (lane == t) mykey = m;
  }
  if (lane < KK_){
    int i = (int)(mykey & 0xffffffffu);
    g_knn[(b*S_+j)*KK_ + lane] = i;
    float rx = __fadd_rn(px[i],-xj), ry = __fadd_rn(py[i],-yj), rz = __fadd_rn(pz[i],-zj);
    float dd = sqrtf(__fadd_rn(__fadd_rn(__fmul_rn(rx,rx), __fmul_rn(ry,ry)), __fmul_rn(rz,rz)));
    float* o = g_ea + ((long)b*E_ + j*KK_ + lane)*4;
    o[0]=rx; o[1]=ry; o[2]=rz; o[3]=dd;
    atomicAdd(&g_indeg[b*S_+i], 1);
  }
}

__global__ void k_scan(){
  __shared__ int sA[2048], sB[2048];
  int b = blockIdx.x, tid = threadIdx.x;   // 1024
  for (int i = tid; i < 2048; i += 1024) sA[i] = (i < S_) ? g_indeg[b*S_+i] : 0;
  __syncthreads();
  int *src = sA, *dst = sB;
  for (int d = 1; d < 2048; d <<= 1){
    for (int i = tid; i < 2048; i += 1024) dst[i] = src[i] + (i >= d ? src[i-d] : 0);
    __syncthreads();
    int* t2 = src; src = dst; dst = t2;
  }
  if (tid == 0) g_off[b*(S_+1)] = 0;
  for (int i = tid; i < S_; i += 1024) g_off[b*(S_+1)+i+1] = src[i];
}

__global__ void k_fill(){
  int idx = blockIdx.x*256 + threadIdx.x;
  if (idx >= B_*E_) return;
  int b = idx / E_, e = idx - b*E_;
  int i = g_knn[idx];
  int slot = atomicAdd(&g_cursor[b*S_+i], 1);
  g_list[b*E_ + g_off[b*(S_+1)+i] + slot] = e;
}

// ---------------- weight packing (MFMA B-operand fragment order) ----------------
__global__ void k_pack_w2(const void* __restrict__ c0w2, const void* __restrict__ cw2,
                          const void* __restrict__ hw1){
  int gi = blockIdx.x*256 + threadIdx.x;
  if (gi >= 11*H_*H_) return;
  int mat = gi / (H_*H_), r = gi - mat*(H_*H_);
  int k = r / H_, n = r - (r/H_)*H_;
  float v;
  if (mat == 0)      v = LD(c0w2, (long)k*H_ + n);
  else if (mat <= 9) v = LD(cw2, (long)(mat-1)*H_*H_ + (long)k*H_ + n);
  else               v = LD(hw1, (long)k*H_ + n);
  int t = k>>5, q = (k>>3)&3, jj = k&7;
  g_w2p[(size_t)mat*H_*H_ + (((t*4+q)*H_ + n)*8 + jj)] = __float2bfloat16(v);
}

__global__ void k_pack_wc(const void* __restrict__ cw1){
  int gi = blockIdx.x*256 + threadIdx.x;
  if (gi >= 9*H_*384) return;
  int l = gi / (H_*384), r = gi - l*(H_*384);
  int k = r / 384, n = r - (r/384)*384;
  long base = (long)l*388*H_;
  float v;
  if (n < H_) v = LD(cw1, base + (long)k*H_ + n) - LD(cw1, base + (long)(H_+k)*H_ + n);
  else        v = LD(cw1, base + (long)(H_+k)*H_ + (n-H_));
  int t = k>>5, q = (k>>3)&3, jj = k&7;
  g_wcp[(size_t)l*(H_*384) + (((t*4+q)*384 + n)*8 + jj)] = __float2bfloat16(v);
}

// ---------------- conv0 node projection (K=10) ----------------
__global__ void k_proj0(const void* __restrict__ w1){
  int gi = blockIdx.x*256 + threadIdx.x;
  if (gi >= NROW*384) return;
  int row = gi / 384, n = gi - (gi/384)*384;
  const float* x = g_x0 + (size_t)row*10;
  float acc = 0.f;
  if (n < H_){
    #pragma unroll
    for (int f = 0; f < 10; ++f) acc += x[f] * (LD(w1, f*H_+n) - LD(w1, (10+f)*H_+n));
  } else {
    int hc = n - H_;
    #pragma unroll
    for (int f = 0; f < 10; ++f) acc += x[f] * LD(w1, (10+f)*H_+hc);
  }
  g_PQ[(size_t)row*384 + n] = acc;
}

// ---------------- MFMA GEMM, K=192 ----------------
// MODE 0: A=g_hbf, B=g_wcp+off, N=384 -> f32 g_PQ
// MODE 1: A=g_m1,  B=g_w2p+off, N=192 -> +bias, bf16 g_m2
// MODE 2: A=g_hh,  B=g_w2p+off, N=192 -> +bias, gelu, bf16 g_t
template<int NT, int MODE>
__global__ __launch_bounds__(256) void k_gemm192(const void* __restrict__ biasB, long biasO,
                                                 int bOff, int M){
  constexpr int N = NT*64;
  const bf* A  = (MODE == 0) ? g_hbf : (MODE == 1 ? g_m1 : g_hh);
  const bf* Bp = ((MODE == 0) ? g_wcp : g_w2p) + bOff;
  int wave = threadIdx.x >> 6, lane = threadIdx.x & 63;
  int q = lane >> 4, l16 = lane & 15;
  long rowBase = (long)blockIdx.x * 64;
  f32x4 acc[4][NT];
  #pragma unroll
  for (int rt = 0; rt < 4; ++rt)
    #pragma unroll
    for (int ct = 0; ct < NT; ++ct) acc[rt][ct] = (f32x4){0.f,0.f,0.f,0.f};
  #pragma unroll
  for (int t = 0; t < 6; ++t){
    int kof = t*32 + q*8;
    bf16x8 af[4], bfr[NT];
    #pragma unroll
    for (int rt = 0; rt < 4; ++rt){
      long r = rowBase + rt*16 + l16;
      if (r >= M) r = M-1;
      af[rt] = *reinterpret_cast<const bf16x8*>(A + r*192 + kof);
    }
    #pragma unroll
    for (int ct = 0; ct < NT; ++ct){
      int n = wave*(NT*16) + ct*16 + l16;
      bfr[ct] = *reinterpret_cast<const bf16x8*>(Bp + (((t*4+q)*N + n)*8));
    }
    #pragma unroll
    for (int rt = 0; rt < 4; ++rt)
      #pragma unroll
      for (int ct = 0; ct < NT; ++ct)
        acc[rt][ct] = __builtin_amdgcn_mfma_f32_16x16x32_bf16(af[rt], bfr[ct], acc[rt][ct], 0,0,0);
  }
  #pragma unroll
  for (int rt = 0; rt < 4; ++rt){
    #pragma unroll
    for (int ct = 0; ct < NT; ++ct){
      int col = wave*(NT*16) + ct*16 + l16;
      float bb = (MODE == 0) ? 0.f : LD(biasB, biasO + col);
      #pragma unroll
      for (int r = 0; r < 4; ++r){
        long row = rowBase + rt*16 + q*4 + r;
        if (row < M){
          float v = acc[rt][ct][r];
          if constexpr (MODE == 0) g_PQ[row*384 + col] = v;
          if constexpr (MODE == 1){ g_m2[row*192 + col] = __float2bfloat16(v + bb); }
          if constexpr (MODE == 2){ g_t[row*192 + col] = __float2bfloat16(gelu_f(v + bb)); }
        }
      }
    }
  }
}

// ---------------- per-edge m1 = gelu(P[i]+Q[j]+ea@w1c+b1), 8 edges/block ----------------
__global__ __launch_bounds__(192) void k_edge(const void* __restrict__ w1cB, long w1cO,
                                              const void* __restrict__ b1B, long b1O){
  int col = threadIdx.x;
  long base = (long)blockIdx.x * 8;
  float w0 = LD(w1cB, w1cO+col),      w1v = LD(w1cB, w1cO+H_+col);
  float w2v = LD(w1cB, w1cO+2*H_+col), w3v = LD(w1cB, w1cO+3*H_+col);
  float bb = LD(b1B, b1O + col);
  #pragma unroll
  for (int r = 0; r < 8; ++r){
    long row = base + r;
    int bk = (int)(row / E_); int e = (int)(row - (long)bk*E_); int b = bk >> 1;
    int j = e >> 4;
    int i = g_knn[b*E_ + e];
    float pv = g_PQ[((size_t)(bk*S_ + i))*384 + col];
    float qv = g_PQ[((size_t)(bk*S_ + j))*384 + 192 + col];
    const float* ep = g_ea + ((size_t)b*E_ + e)*4;
    float acc = pv + qv + bb + ep[0]*w0 + ep[1]*w1v + ep[2]*w2v + ep[3]*w3v;
    g_m1[(size_t)row*H_ + col] = __float2bfloat16(gelu_f(acc));
  }
}

// ---------------- CSR aggregate + LayerNorm (+residual) ----------------
template<int RES>
__global__ void k_aggln(const void* __restrict__ gB, long gO,
                        const void* __restrict__ beB, long beO){
  int row = blockIdx.x;   // NROW
  int col = threadIdx.x;  // 192
  int bk = row / S_, i = row - bk*S_, b = bk >> 1;
  int off = g_off[b*(S_+1)+i];
  int deg = g_off[b*(S_+1)+i+1] - off;
  float acc = 0.f;
  for (int d = 0; d < deg; ++d){
    int e = g_list[b*E_ + off + d];
    acc += bf2f(g_m2[((size_t)bk*E_ + e)*H_ + col]);
  }
  float s = acc, qq = acc*acc;
  #pragma unroll
  for (int o = 32; o; o >>= 1){ s += __shfl_xor(s,o,64); qq += __shfl_xor(qq,o,64); }
  __shared__ float ws[3][2];
  int wid = col >> 6, lane = col & 63;
  if (!lane){ ws[wid][0]=s; ws[wid][1]=qq; }
  __syncthreads();
  float Sm = ws[0][0]+ws[1][0]+ws[2][0];
  float Qm = ws[0][1]+ws[1][1]+ws[2][1];
  float mu = Sm*(1.f/H_);
  float var = Qm*(1.f/H_) - mu*mu;
  float rstd = rsqrtf(fmaxf(var, 0.f) + 1e-5f);
  float y = (acc-mu)*rstd*LD(gB,gO+col) + LD(beB,beO+col);
  if (RES) y += g_h[(size_t)row*H_ + col];
  g_h[(size_t)row*H_ + col] = y;
  g_hbf[(size_t)row*H_ + col] = __float2bfloat16(y);
}

__global__ void k_lnhead(const void* __restrict__ g, const void* __restrict__ be){
  int row = blockIdx.x;
  int col = threadIdx.x;
  float x = g_h[(size_t)row*H_ + col];
  float s = x, qq = x*x;
  #pragma unroll
  for (int o = 32; o; o >>= 1){ s += __shfl_xor(s,o,64); qq += __shfl_xor(qq,o,64); }
  __shared__ float ws[3][2];
  int wid = col >> 6, lane = col & 63;
  if (!lane){ ws[wid][0]=s; ws[wid][1]=qq; }
  __syncthreads();
  float Sm = ws[0][0]+ws[1][0]+ws[2][0];
  float Qm = ws[0][1]+ws[1][1]+ws[2][1];
  float mu = Sm*(1.f/H_);
  float var = Qm*(1.f/H_) - mu*mu;
  float rstd = rsqrtf(fmaxf(var, 0.f) + 1e-5f);
  g_hh[(size_t)row*H_ + col] = __float2bfloat16((x-mu)*rstd*LD(g,col) + LD(be,col));
}

// ---------------- output (fp32) ----------------
__global__ void k_initout(const void* __restrict__ ub, const void* __restrict__ air, float* __restrict__ out){
  int gi = blockIdx.x*256 + threadIdx.x;   // 49152
  int n = (gi/3) % NN_;
  int b = gi / (K_*NN_*C_);
  float a = 1.f - LD(air, b*NN_+n);
  out[gi] = LD(ub, gi) * a;
}

__global__ void k_headout(const void* __restrict__ w2, const void* __restrict__ b2,
                          const void* __restrict__ ub, const void* __restrict__ air,
                          float* __restrict__ out){
  int row = blockIdx.x*4 + (threadIdx.x >> 6);
  int lane = threadIdx.x & 63;
  if (row >= NROW) return;
  float t0 = bf2f(g_t[(size_t)row*H_ + lane]);
  float t1 = bf2f(g_t[(size_t)row*H_ + lane + 64]);
  float t2 = bf2f(g_t[(size_t)row*H_ + lane + 128]);
  float d[3];
  #pragma unroll
  for (int c = 0; c < 3; ++c){
    float p = t0*LD(w2,lane*3+c) + t1*LD(w2,(lane+64)*3+c) + t2*LD(w2,(lane+128)*3+c);
    #pragma unroll
    for (int o = 32; o; o >>= 1) p += __shfl_xor(p,o,64);
    d[c] = p + LD(b2,c);
  }
  if (lane == 0){
    int bk = row / S_, s = row - bk*S_, b = bk >> 1;
    float msk = g_masksel[b*S_+s];
    int node = g_topidx[b*S_+s];
    float am = 1.f - LD(air, b*NN_+node);
    #pragma unroll
    for (int c = 0; c < 3; ++c){
      long oi = ((long)bk*NN_ + node)*3 + c;
      out[oi] = (LD(ub,oi) + d[c]*msk)*am;
    }
  }
}

extern "C" void kernel_launch(void* const* d_in, const int* in_sizes, int n_in,
                              void* d_out, int out_size, void* d_ws, size_t ws_size,
                              hipStream_t stream) {
  (void)in_sizes; (void)n_in; (void)d_ws; (void)ws_size; (void)out_size;
  const void* u_base = d_in[0];
  const void* pos    = d_in[1];
  const void* vel    = d_in[2];
  const void* air    = d_in[3];
  const void* c0w1   = d_in[4];
  const void* c0b1   = d_in[5];
  const void* c0w2   = d_in[6];
  const void* c0b2   = d_in[7];
  const void* c0g    = d_in[8];
  const void* c0be   = d_in[9];
  const void* cw1    = d_in[10];
  const void* cb1    = d_in[11];
  const void* cw2    = d_in[12];
  const void* cb2    = d_in[13];
  const void* cg     = d_in[14];
  const void* cbe    = d_in[15];
  const void* hg     = d_in[16];
  const void* hbe    = d_in[17];
  const void* hw1    = d_in[18];
  const void* hb1    = d_in[19];
  const void* hw2    = d_in[20];
  const void* hb2    = d_in[21];
  float* out = (float*)d_out;

  k_viol<<<1, 256, 0, stream>>>(u_base, pos, vel);
  k_zero<<<13, 256, 0, stream>>>();
  k_var<<<dim3(16, B_), 256, 0, stream>>>(vel);
  k_soft<<<dim3(16, B_), 256, 0, stream>>>(air);
  k_rank<<<dim3(16, B_), 256, 0, stream>>>();
  k_gather<<<13, 256, 0, stream>>>(pos, u_base, vel);
  k_knn<<<dim3((S_+3)/4, B_), 256, 0, stream>>>();
  k_scan<<<B_, 1024, 0, stream>>>();
  k_fill<<<205, 256, 0, stream>>>();
  k_pack_w2<<<1584, 256, 0, stream>>>(c0w2, cw2, hw1);
  k_pack_wc<<<2592, 256, 0, stream>>>(cw1);
  k_initout<<<192, 256, 0, stream>>>(u_base, air, out);
  k_proj0<<<9828, 256, 0, stream>>>(c0w1);

  for (int l = 0; l < 10; ++l){
    if (l > 0) k_gemm192<6,0><<<103, 256, 0, stream>>>(nullptr, 0, (l-1)*H_*384, NROW);

    long w1cO = (l == 0) ? 20L*H_ : ((long)(l-1)*388 + 384)*H_;
    const void* w1cB = (l == 0) ? c0w1 : cw1;
    long lOff = (l == 0) ? 0 : (long)(l-1)*H_;
    const void* b1B = (l == 0) ? c0b1 : cb1;
    k_edge<<<EROW/8, 192, 0, stream>>>(w1cB, w1cO, b1B, lOff);

    const void* b2B = (l == 0) ? c0b2 : cb2;
    k_gemm192<3,1><<<EROW/64, 256, 0, stream>>>(b2B, lOff, l*H_*H_, EROW);

    const void* gB  = (l == 0) ? c0g  : cg;
    const void* beB = (l == 0) ? c0be : cbe;
    if (l > 0) k_aggln<1><<<NROW, 192, 0, stream>>>(gB, lOff, beB, lOff);
    else       k_aggln<0><<<NROW, 192, 0, stream>>>(gB, lOff, beB, lOff);
  }

  k_lnhead<<<NROW, 192, 0, stream>>>(hg, hbe);
  k_gemm192<3,2><<<103, 256, 0, stream>>>(hb1, 0, 10*H_*H_, NROW);
  k_headout<<<NROW/4, 256, 0, stream>>>(hw2, hb2, u_base, air, out);
}

// Round 7
// 763.984 us; speedup vs baseline: 7.4793x; 1.7837x over previous
//
#include <hip/hip_runtime.h>
#include <hip/hip_bf16.h>
#include <math.h>

#define B_ 2
#define K_ 2
#define NN_ 4096
#define T_ 8
#define C_ 3
#define H_ 192
#define S_ 1638
#define KK_ 16
#define E_ (S_*KK_)          // 26208
#define NROW (B_*K_*S_)      // 6552
#define EROW (B_*K_*E_)      // 104832
#define SHARP_ 5.0f

typedef __hip_bfloat16 bf;
typedef unsigned long long ull;
typedef __bf16 bf16x8 __attribute__((ext_vector_type(8)));
typedef float f32x4 __attribute__((ext_vector_type(4)));

__device__ int   g_isbf16;
__device__ int   g_viol;
__device__ __align__(16) float g_var[B_*NN_];
__device__ __align__(16) float g_soft[B_*NN_];
__device__ __align__(16) float g_accum[B_*2];
__device__ __align__(16) int   g_topidx[B_*S_];
__device__ __align__(16) float g_possel[B_*S_*3];
__device__ __align__(16) float g_masksel[B_*S_];
__device__ __align__(16) float g_x0[NROW*10];
__device__ __align__(16) int   g_knn[B_*E_];
__device__ __align__(16) float g_ea[B_*E_*4];
__device__ __align__(16) int   g_indeg[B_*S_];
__device__ __align__(16) int   g_cursor[B_*S_];
__device__ __align__(16) int   g_off[B_*(S_+1)];
__device__ __align__(16) int   g_list[B_*E_];
__device__ __align__(16) float g_PQ[(size_t)NROW*384];
__device__ __align__(16) float g_h[(size_t)NROW*H_];
__device__ __align__(16) bf    g_hbf[(size_t)NROW*H_];
__device__ __align__(16) bf    g_abf[(size_t)NROW*H_];     // aggregated gelu sums (bf16)
__device__ __align__(16) float g_m2n[(size_t)NROW*H_];     // node-level m2 (fp32)
__device__ __align__(16) bf    g_hh[(size_t)NROW*H_];
__device__ __align__(16) bf    g_t[(size_t)NROW*H_];
__device__ __align__(16) bf    g_w2p[(size_t)11*H_*H_];
__device__ __align__(16) bf    g_wcp[(size_t)9*H_*384];

__device__ __forceinline__ float bf2f(bf x){ return __bfloat162float(x); }
__device__ __forceinline__ float LD(const void* p, long i){
  return g_isbf16 ? __bfloat162float(((const bf*)p)[i]) : ((const float*)p)[i];
}
__device__ __forceinline__ float gelu_f(float x){ return 0.5f*x*(1.0f + erff(x*0.70710678118654752f)); }
__device__ __forceinline__ ull shfl_xor_u64(ull v, int m){
  unsigned lo = (unsigned)v, hi = (unsigned)(v >> 32);
  lo = __shfl_xor(lo, m, 64); hi = __shfl_xor(hi, m, 64);
  return ((ull)hi << 32) | lo;
}

// ---------------- input dtype detect ----------------
__global__ void k_viol(const void* a, const void* b, const void* c){
  int t = threadIdx.x;
  const bf* pa = (const bf*)a; const bf* pb = (const bf*)b; const bf* pc = (const bf*)c;
  int bad = 0;
  #pragma unroll
  for (int s = 0; s < 2; ++s){
    float va = __bfloat162float(pa[t + s*256]);
    float vb = __bfloat162float(pb[t + s*256]);
    float vc = __bfloat162float(pc[t + s*256]);
    if (!(fabsf(va) <= 1000.f)) bad = 1;
    if (!(fabsf(vb) <= 1000.f)) bad = 1;
    if (!(fabsf(vc) <= 1000.f)) bad = 1;
  }
  if (threadIdx.x == 0) g_viol = 0;
  __syncthreads();
  if (bad) atomicOr(&g_viol, 1);
  __syncthreads();
  if (threadIdx.x == 0) g_isbf16 = (g_viol == 0) ? 1 : 0;
}

__global__ void k_zero(){
  int tid = blockIdx.x*256 + threadIdx.x;
  if (tid < B_*S_){ g_indeg[tid]=0; g_cursor[tid]=0; }
  if (tid < B_*2) g_accum[tid]=0.f;
}

// ---------------- var_pp, np pairwise-8 semantics ----------------
__global__ void k_var(const void* __restrict__ vel){
  int b = blockIdx.y;
  int n = blockIdx.x*256 + threadIdx.x;
  float v = 0.f;
  #pragma unroll
  for (int c = 0; c < 3; ++c){
    float x[8];
    #pragma unroll
    for (int t = 0; t < 8; ++t)
      x[t] = LD(vel, ((long)(b*T_+t)*NN_ + n)*3 + c);
    float m = __fadd_rn(__fadd_rn(__fadd_rn(x[0],x[1]), __fadd_rn(x[2],x[3])),
                        __fadd_rn(__fadd_rn(x[4],x[5]), __fadd_rn(x[6],x[7]))) / 8.0f;
    float d[8];
    #pragma unroll
    for (int t = 0; t < 8; ++t){ float dd = __fadd_rn(x[t], -m); d[t] = __fmul_rn(dd,dd); }
    float sv = __fadd_rn(__fadd_rn(__fadd_rn(d[0],d[1]), __fadd_rn(d[2],d[3])),
                         __fadd_rn(__fadd_rn(d[4],d[5]), __fadd_rn(d[6],d[7])));
    v = __fadd_rn(v, sv / 7.0f);
  }
  g_var[b*NN_ + n] = v;
  float s1 = v, s2 = v*v;
  #pragma unroll
  for (int o = 32; o; o >>= 1){ s1 += __shfl_xor(s1,o,64); s2 += __shfl_xor(s2,o,64); }
  __shared__ float r1[4], r2[4];
  int lane = threadIdx.x & 63, wid = threadIdx.x >> 6;
  if (!lane){ r1[wid]=s1; r2[wid]=s2; }
  __syncthreads();
  if (threadIdx.x == 0){
    atomicAdd(&g_accum[b*2+0], r1[0]+r1[1]+r1[2]+r1[3]);
    atomicAdd(&g_accum[b*2+1], r2[0]+r2[1]+r2[2]+r2[3]);
  }
}

__global__ void k_soft(const void* __restrict__ air){
  int b = blockIdx.y;
  int n = blockIdx.x*256 + threadIdx.x;
  float S1 = g_accum[b*2], S2 = g_accum[b*2+1];
  float mean = S1*(1.f/NN_);
  float sd = sqrtf(fmaxf((S2 - S1*S1*(1.f/NN_))*(1.f/(NN_-1)), 0.f));
  float v = g_var[b*NN_+n];
  float z = (v-mean)/(sd+1e-8f);
  float sig = 1.f/(1.f+expf(-SHARP_*z));
  g_soft[b*NN_+n] = sig*(1.f - LD(air, b*NN_+n));
}

// ---------------- stable rank-based top-S: one wave per node ----------------
__global__ __launch_bounds__(256) void k_rank(){
  int b = blockIdx.y;
  int i = blockIdx.x*4 + (threadIdx.x >> 6);
  int lane = threadIdx.x & 63;
  float vi = g_var[b*NN_+i];
  int rank = 0;
  for (int j = lane; j < NN_; j += 64){
    float vj = g_var[b*NN_+j];
    rank += ((vj > vi) || (vj == vi && j < i)) ? 1 : 0;
  }
  #pragma unroll
  for (int o = 32; o; o >>= 1) rank += __shfl_xor(rank, o, 64);
  if (lane == 0 && rank < S_) g_topidx[b*S_ + rank] = i;
}

__global__ void k_gather(const void* __restrict__ pos, const void* __restrict__ ub,
                         const void* __restrict__ vel){
  int gi = blockIdx.x*256 + threadIdx.x;
  if (gi >= B_*S_) return;
  int b = gi / S_, s = gi - b*S_;
  int node = g_topidx[gi];
  float px = LD(pos, ((long)b*NN_+node)*3+0);
  float py = LD(pos, ((long)b*NN_+node)*3+1);
  float pz = LD(pos, ((long)b*NN_+node)*3+2);
  g_possel[gi*3+0]=px; g_possel[gi*3+1]=py; g_possel[gi*3+2]=pz;
  g_masksel[gi] = g_soft[b*NN_+node];
  float vf = g_var[b*NN_+node];
  float vl0 = LD(vel, ((long)(b*T_+7)*NN_+node)*3+0);
  float vl1 = LD(vel, ((long)(b*T_+7)*NN_+node)*3+1);
  float vl2 = LD(vel, ((long)(b*T_+7)*NN_+node)*3+2);
  for (int k = 0; k < K_; ++k){
    long row = (long)(b*K_+k)*S_ + s;
    float* x = g_x0 + row*10;
    x[0]=LD(ub, ((long)(b*K_+k)*NN_+node)*3+0);
    x[1]=LD(ub, ((long)(b*K_+k)*NN_+node)*3+1);
    x[2]=LD(ub, ((long)(b*K_+k)*NN_+node)*3+2);
    x[3]=vl0; x[4]=vl1; x[5]=vl2;
    x[6]=px;  x[7]=py;  x[8]=pz;
    x[9]=vf;
  }
}

// ---------------- KNN: one wave per query node ----------------
__global__ __launch_bounds__(256) void k_knn(){
  __shared__ float px[S_], py[S_], pz[S_];
  int b = blockIdx.y;
  int j = blockIdx.x*4 + (threadIdx.x >> 6);
  int lane = threadIdx.x & 63;
  for (int t = threadIdx.x; t < S_; t += 256){
    px[t] = g_possel[(b*S_+t)*3+0];
    py[t] = g_possel[(b*S_+t)*3+1];
    pz[t] = g_possel[(b*S_+t)*3+2];
  }
  __syncthreads();
  if (j >= S_) return;
  float xj=px[j], yj=py[j], zj=pz[j];
  float dist[KK_]; int id[KK_];
  #pragma unroll
  for (int t = 0; t < KK_; ++t){ dist[t]=3.0e38f; id[t]=0x7fffffff; }
  for (int c = lane; c < S_; c += 64){
    if (c == j) continue;
    float dx=__fadd_rn(px[c],-xj), dy=__fadd_rn(py[c],-yj), dz=__fadd_rn(pz[c],-zj);
    float d2 = __fadd_rn(__fadd_rn(__fmul_rn(dx,dx), __fmul_rn(dy,dy)), __fmul_rn(dz,dz));
    if (d2 < dist[KK_-1]){
      int p = 0;
      #pragma unroll
      for (int q = 0; q < KK_; ++q) p += (dist[q] <= d2) ? 1 : 0;
      #pragma unroll
      for (int q = KK_-1; q >= 1; --q){
        bool mv = (q > p);
        dist[q] = mv ? dist[q-1] : dist[q];
        id[q]   = mv ? id[q-1]   : id[q];
      }
      #pragma unroll
      for (int q = 0; q < KK_; ++q){ if (q == p){ dist[q] = d2; id[q] = c; } }
    }
  }
  ull mykey = 0;
  #pragma unroll
  for (int t = 0; t < KK_; ++t){
    ull k = (((ull)__float_as_uint(dist[0])) << 32) | (unsigned)id[0];
    ull m = k;
    #pragma unroll
    for (int o = 32; o; o >>= 1){ ull other = shfl_xor_u64(m, o); m = (other < m) ? other : m; }
    if (k == m){
      #pragma unroll
      for (int q = 0; q < KK_-1; ++q){ dist[q]=dist[q+1]; id[q]=id[q+1]; }
      dist[KK_-1] = 3.0e38f; id[KK_-1] = 0x7fffffff;
    }
    if (lane == t) mykey = m;
  }
  if (lane < KK_){
    int i = (int)(mykey & 0xffffffffu);
    g_knn[(b*S_+j)*KK_ + lane] = i;
    float rx = __fadd_rn(px[i],-xj), ry = __fadd_rn(py[i],-yj), rz = __fadd_rn(pz[i],-zj);
    float dd = sqrtf(__fadd_rn(__fadd_rn(__fmul_rn(rx,rx), __fmul_rn(ry,ry)), __fmul_rn(rz,rz)));
    float* o = g_ea + ((long)b*E_ + j*KK_ + lane)*4;
    o[0]=rx; o[1]=ry; o[2]=rz; o[3]=dd;
    atomicAdd(&g_indeg[b*S_+i], 1);
  }
}

__global__ void k_scan(){
  __shared__ int sA[2048], sB[2048];
  int b = blockIdx.x, tid = threadIdx.x;   // 1024
  for (int i = tid; i < 2048; i += 1024) sA[i] = (i < S_) ? g_indeg[b*S_+i] : 0;
  __syncthreads();
  int *src = sA, *dst = sB;
  for (int d = 1; d < 2048; d <<= 1){
    for (int i = tid; i < 2048; i += 1024) dst[i] = src[i] + (i >= d ? src[i-d] : 0);
    __syncthreads();
    int* t2 = src; src = dst; dst = t2;
  }
  if (tid == 0) g_off[b*(S_+1)] = 0;
  for (int i = tid; i < S_; i += 1024) g_off[b*(S_+1)+i+1] = src[i];
}

__global__ void k_fill(){
  int idx = blockIdx.x*256 + threadIdx.x;
  if (idx >= B_*E_) return;
  int b = idx / E_, e = idx - b*E_;
  int i = g_knn[idx];
  int slot = atomicAdd(&g_cursor[b*S_+i], 1);
  g_list[b*E_ + g_off[b*(S_+1)+i] + slot] = e;
}

// ---------------- weight packing ----------------
__global__ void k_pack_w2(const void* __restrict__ c0w2, const void* __restrict__ cw2,
                          const void* __restrict__ hw1){
  int gi = blockIdx.x*256 + threadIdx.x;
  if (gi >= 11*H_*H_) return;
  int mat = gi / (H_*H_), r = gi - mat*(H_*H_);
  int k = r / H_, n = r - (r/H_)*H_;
  float v;
  if (mat == 0)      v = LD(c0w2, (long)k*H_ + n);
  else if (mat <= 9) v = LD(cw2, (long)(mat-1)*H_*H_ + (long)k*H_ + n);
  else               v = LD(hw1, (long)k*H_ + n);
  int t = k>>5, q = (k>>3)&3, jj = k&7;
  g_w2p[(size_t)mat*H_*H_ + (((t*4+q)*H_ + n)*8 + jj)] = __float2bfloat16(v);
}

__global__ void k_pack_wc(const void* __restrict__ cw1){
  int gi = blockIdx.x*256 + threadIdx.x;
  if (gi >= 9*H_*384) return;
  int l = gi / (H_*384), r = gi - l*(H_*384);
  int k = r / 384, n = r - (r/384)*384;
  long base = (long)l*388*H_;
  float v;
  if (n < H_) v = LD(cw1, base + (long)k*H_ + n) - LD(cw1, base + (long)(H_+k)*H_ + n);
  else        v = LD(cw1, base + (long)(H_+k)*H_ + (n-H_));
  int t = k>>5, q = (k>>3)&3, jj = k&7;
  g_wcp[(size_t)l*(H_*384) + (((t*4+q)*384 + n)*8 + jj)] = __float2bfloat16(v);
}

// ---------------- conv0 node projection (K=10) ----------------
__global__ void k_proj0(const void* __restrict__ w1){
  int gi = blockIdx.x*256 + threadIdx.x;
  if (gi >= NROW*384) return;
  int row = gi / 384, n = gi - (gi/384)*384;
  const float* x = g_x0 + (size_t)row*10;
  float acc = 0.f;
  if (n < H_){
    #pragma unroll
    for (int f = 0; f < 10; ++f) acc += x[f] * (LD(w1, f*H_+n) - LD(w1, (10+f)*H_+n));
  } else {
    int hc = n - H_;
    #pragma unroll
    for (int f = 0; f < 10; ++f) acc += x[f] * LD(w1, (10+f)*H_+hc);
  }
  g_PQ[(size_t)row*384 + n] = acc;
}

// ---------------- MFMA GEMM, K=192, RT row-tiles of 16 ----------------
// MODE 0: A=g_hbf, B=g_wcp+off, N=384 -> f32 g_PQ
// MODE 1: A=g_abf, B=g_w2p+off, N=192 -> + deg*b2, f32 g_m2n
// MODE 2: A=g_hh,  B=g_w2p+off, N=192 -> +bias, gelu, bf16 g_t
template<int RT, int NT, int MODE>
__global__ __launch_bounds__(256) void k_gemm192(const void* __restrict__ biasB, long biasO,
                                                 int bOff, int M){
  constexpr int N = NT*64;
  const bf* A  = (MODE == 0) ? g_hbf : (MODE == 1 ? g_abf : g_hh);
  const bf* Bp = ((MODE == 0) ? g_wcp : g_w2p) + bOff;
  int wave = threadIdx.x >> 6, lane = threadIdx.x & 63;
  int q = lane >> 4, l16 = lane & 15;
  long rowBase = (long)blockIdx.x * (RT*16);
  f32x4 acc[RT][NT];
  #pragma unroll
  for (int rt = 0; rt < RT; ++rt)
    #pragma unroll
    for (int ct = 0; ct < NT; ++ct) acc[rt][ct] = (f32x4){0.f,0.f,0.f,0.f};
  #pragma unroll
  for (int t = 0; t < 6; ++t){
    int kof = t*32 + q*8;
    bf16x8 af[RT], bfr[NT];
    #pragma unroll
    for (int rt = 0; rt < RT; ++rt){
      long r = rowBase + rt*16 + l16;
      if (r >= M) r = M-1;
      af[rt] = *reinterpret_cast<const bf16x8*>(A + r*192 + kof);
    }
    #pragma unroll
    for (int ct = 0; ct < NT; ++ct){
      int n = wave*(NT*16) + ct*16 + l16;
      bfr[ct] = *reinterpret_cast<const bf16x8*>(Bp + (((t*4+q)*N + n)*8));
    }
    #pragma unroll
    for (int rt = 0; rt < RT; ++rt)
      #pragma unroll
      for (int ct = 0; ct < NT; ++ct)
        acc[rt][ct] = __builtin_amdgcn_mfma_f32_16x16x32_bf16(af[rt], bfr[ct], acc[rt][ct], 0,0,0);
  }
  #pragma unroll
  for (int rt = 0; rt < RT; ++rt){
    #pragma unroll
    for (int ct = 0; ct < NT; ++ct){
      int col = wave*(NT*16) + ct*16 + l16;
      float bb = 0.f;
      if constexpr (MODE != 0) bb = LD(biasB, biasO + col);
      #pragma unroll
      for (int r = 0; r < 4; ++r){
        long row = rowBase + rt*16 + q*4 + r;
        if (row < M){
          float v = acc[rt][ct][r];
          if constexpr (MODE == 0) g_PQ[row*384 + col] = v;
          if constexpr (MODE == 1){
            int bk = (int)(row / S_); int i = (int)(row - (long)bk*S_); int b = bk >> 1;
            float degf = (float)(g_off[b*(S_+1)+i+1] - g_off[b*(S_+1)+i]);
            g_m2n[row*192 + col] = v + degf*bb;
          }
          if constexpr (MODE == 2){ g_t[row*192 + col] = __float2bfloat16(gelu_f(v + bb)); }
        }
      }
    }
  }
}

// ---------------- fused edge-compute + CSR aggregate ----------------
// A[i] = sum_e gelu(P[i] + Q[j_e] + ea_e@w1c + b1), one block per node row
__global__ __launch_bounds__(192) void k_aggedge(const void* __restrict__ w1cB, long w1cO,
                                                 const void* __restrict__ b1B, long b1O){
  int row = blockIdx.x;   // NROW
  int col = threadIdx.x;  // 192
  int bk = row / S_, i = row - bk*S_, b = bk >> 1;
  int off = g_off[b*(S_+1)+i];
  int deg = g_off[b*(S_+1)+i+1] - off;
  float w0 = LD(w1cB, w1cO+col),       w1v = LD(w1cB, w1cO+H_+col);
  float w2v = LD(w1cB, w1cO+2*H_+col), w3v = LD(w1cB, w1cO+3*H_+col);
  float base = g_PQ[(size_t)row*384 + col] + LD(b1B, b1O+col);
  float acc = 0.f;
  for (int d = 0; d < deg; ++d){
    int e = g_list[b*E_ + off + d];
    int j = e >> 4;
    const float* ep = g_ea + ((size_t)b*E_ + e)*4;
    float qv = g_PQ[((size_t)(bk*S_ + j))*384 + 192 + col];
    float m = base + qv + ep[0]*w0 + ep[1]*w1v + ep[2]*w2v + ep[3]*w3v;
    acc += gelu_f(m);
  }
  g_abf[(size_t)row*H_ + col] = __float2bfloat16(acc);
}

// ---------------- LayerNorm (+residual) over node m2 ----------------
template<int RES>
__global__ void k_ln(const void* __restrict__ gB, long gO,
                     const void* __restrict__ beB, long beO){
  int row = blockIdx.x;   // NROW
  int col = threadIdx.x;  // 192
  float x = g_m2n[(size_t)row*H_ + col];
  float s = x, qq = x*x;
  #pragma unroll
  for (int o = 32; o; o >>= 1){ s += __shfl_xor(s,o,64); qq += __shfl_xor(qq,o,64); }
  __shared__ float ws[3][2];
  int wid = col >> 6, lane = col & 63;
  if (!lane){ ws[wid][0]=s; ws[wid][1]=qq; }
  __syncthreads();
  float Sm = ws[0][0]+ws[1][0]+ws[2][0];
  float Qm = ws[0][1]+ws[1][1]+ws[2][1];
  float mu = Sm*(1.f/H_);
  float var = Qm*(1.f/H_) - mu*mu;
  float rstd = rsqrtf(fmaxf(var, 0.f) + 1e-5f);
  float y = (x-mu)*rstd*LD(gB,gO+col) + LD(beB,beO+col);
  if (RES) y += g_h[(size_t)row*H_ + col];
  g_h[(size_t)row*H_ + col] = y;
  g_hbf[(size_t)row*H_ + col] = __float2bfloat16(y);
}

__global__ void k_lnhead(const void* __restrict__ g, const void* __restrict__ be){
  int row = blockIdx.x;
  int col = threadIdx.x;
  float x = g_h[(size_t)row*H_ + col];
  float s = x, qq = x*x;
  #pragma unroll
  for (int o = 32; o; o >>= 1){ s += __shfl_xor(s,o,64); qq += __shfl_xor(qq,o,64); }
  __shared__ float ws[3][2];
  int wid = col >> 6, lane = col & 63;
  if (!lane){ ws[wid][0]=s; ws[wid][1]=qq; }
  __syncthreads();
  float Sm = ws[0][0]+ws[1][0]+ws[2][0];
  float Qm = ws[0][1]+ws[1][1]+ws[2][1];
  float mu = Sm*(1.f/H_);
  float var = Qm*(1.f/H_) - mu*mu;
  float rstd = rsqrtf(fmaxf(var, 0.f) + 1e-5f);
  g_hh[(size_t)row*H_ + col] = __float2bfloat16((x-mu)*rstd*LD(g,col) + LD(be,col));
}

// ---------------- output (fp32) ----------------
__global__ void k_initout(const void* __restrict__ ub, const void* __restrict__ air, float* __restrict__ out){
  int gi = blockIdx.x*256 + threadIdx.x;   // 49152
  int n = (gi/3) % NN_;
  int b = gi / (K_*NN_*C_);
  float a = 1.f - LD(air, b*NN_+n);
  out[gi] = LD(ub, gi) * a;
}

__global__ void k_headout(const void* __restrict__ w2, const void* __restrict__ b2,
                          const void* __restrict__ ub, const void* __restrict__ air,
                          float* __restrict__ out){
  int row = blockIdx.x*4 + (threadIdx.x >> 6);
  int lane = threadIdx.x & 63;
  if (row >= NROW) return;
  float t0 = bf2f(g_t[(size_t)row*H_ + lane]);
  float t1 = bf2f(g_t[(size_t)row*H_ + lane + 64]);
  float t2 = bf2f(g_t[(size_t)row*H_ + lane + 128]);
  float d[3];
  #pragma unroll
  for (int c = 0; c < 3; ++c){
    float p = t0*LD(w2,lane*3+c) + t1*LD(w2,(lane+64)*3+c) + t2*LD(w2,(lane+128)*3+c);
    #pragma unroll
    for (int o = 32; o; o >>= 1) p += __shfl_xor(p,o,64);
    d[c] = p + LD(b2,c);
  }
  if (lane == 0){
    int bk = row / S_, s = row - bk*S_, b = bk >> 1;
    float msk = g_masksel[b*S_+s];
    int node = g_topidx[b*S_+s];
    float am = 1.f - LD(air, b*NN_+node);
    #pragma unroll
    for (int c = 0; c < 3; ++c){
      long oi = ((long)bk*NN_ + node)*3 + c;
      out[oi] = (LD(ub,oi) + d[c]*msk)*am;
    }
  }
}

extern "C" void kernel_launch(void* const* d_in, const int* in_sizes, int n_in,
                              void* d_out, int out_size, void* d_ws, size_t ws_size,
                              hipStream_t stream) {
  (void)in_sizes; (void)n_in; (void)d_ws; (void)ws_size; (void)out_size;
  const void* u_base = d_in[0];
  const void* pos    = d_in[1];
  const void* vel    = d_in[2];
  const void* air    = d_in[3];
  const void* c0w1   = d_in[4];
  const void* c0b1   = d_in[5];
  const void* c0w2   = d_in[6];
  const void* c0b2   = d_in[7];
  const void* c0g    = d_in[8];
  const void* c0be   = d_in[9];
  const void* cw1    = d_in[10];
  const void* cb1    = d_in[11];
  const void* cw2    = d_in[12];
  const void* cb2    = d_in[13];
  const void* cg     = d_in[14];
  const void* cbe    = d_in[15];
  const void* hg     = d_in[16];
  const void* hbe    = d_in[17];
  const void* hw1    = d_in[18];
  const void* hb1    = d_in[19];
  const void* hw2    = d_in[20];
  const void* hb2    = d_in[21];
  float* out = (float*)d_out;

  k_viol<<<1, 256, 0, stream>>>(u_base, pos, vel);
  k_zero<<<13, 256, 0, stream>>>();
  k_var<<<dim3(16, B_), 256, 0, stream>>>(vel);
  k_soft<<<dim3(16, B_), 256, 0, stream>>>(air);
  k_rank<<<dim3(NN_/4, B_), 256, 0, stream>>>();
  k_gather<<<13, 256, 0, stream>>>(pos, u_base, vel);
  k_knn<<<dim3((S_+3)/4, B_), 256, 0, stream>>>();
  k_scan<<<B_, 1024, 0, stream>>>();
  k_fill<<<205, 256, 0, stream>>>();
  k_pack_w2<<<1584, 256, 0, stream>>>(c0w2, cw2, hw1);
  k_pack_wc<<<2592, 256, 0, stream>>>(cw1);
  k_initout<<<192, 256, 0, stream>>>(u_base, air, out);
  k_proj0<<<9828, 256, 0, stream>>>(c0w1);

  const int GN = (NROW + 31) / 32;   // 205 blocks, 32 rows each
  for (int l = 0; l < 10; ++l){
    if (l > 0) k_gemm192<2,6,0><<<GN, 256, 0, stream>>>(c0b1, 0, (l-1)*H_*384, NROW);

    long w1cO = (l == 0) ? 20L*H_ : ((long)(l-1)*388 + 384)*H_;
    const void* w1cB = (l == 0) ? c0w1 : cw1;
    long lOff = (l == 0) ? 0 : (long)(l-1)*H_;
    const void* b1B = (l == 0) ? c0b1 : cb1;
    k_aggedge<<<NROW, 192, 0, stream>>>(w1cB, w1cO, b1B, lOff);

    const void* b2B = (l == 0) ? c0b2 : cb2;
    k_gemm192<2,3,1><<<GN, 256, 0, stream>>>(b2B, lOff, l*H_*H_, NROW);

    const void* gB  = (l == 0) ? c0g  : cg;
    const void* beB = (l == 0) ? c0be : cbe;
    if (l > 0) k_ln<1><<<NROW, 192, 0, stream>>>(gB, lOff, beB, lOff);
    else       k_ln<0><<<NROW, 192, 0, stream>>>(gB, lOff, beB, lOff);
  }

  k_lnhead<<<NROW, 192, 0, stream>>>(hg, hbe);
  k_gemm192<2,3,2><<<GN, 256, 0, stream>>>(hb1, 0, 10*H_*H_, NROW);
  k_headout<<<NROW/4, 256, 0, stream>>>(hw2, hb2, u_base, air, out);
}

// Round 8
// 679.477 us; speedup vs baseline: 8.4095x; 1.1244x over previous
//
#include <hip/hip_runtime.h>
#include <hip/hip_bf16.h>
#include <math.h>

#define B_ 2
#define K_ 2
#define NN_ 4096
#define T_ 8
#define C_ 3
#define H_ 192
#define S_ 1638
#define KK_ 16
#define E_ (S_*KK_)          // 26208
#define NROW (B_*K_*S_)      // 6552
#define SHARP_ 5.0f

typedef __hip_bfloat16 bf;
typedef unsigned long long ull;
typedef __bf16 bf16x8 __attribute__((ext_vector_type(8)));
typedef float f32x4 __attribute__((ext_vector_type(4)));

__device__ int   g_isbf16;
__device__ int   g_viol;
__device__ __align__(16) float g_var[B_*NN_];
__device__ __align__(16) float g_soft[B_*NN_];
__device__ __align__(16) float g_accum[B_*2];
__device__ __align__(16) int   g_topidx[B_*S_];
__device__ __align__(16) float g_possel[B_*S_*3];
__device__ __align__(16) float g_masksel[B_*S_];
__device__ __align__(16) float g_x0[NROW*10];
__device__ __align__(16) int   g_knn[B_*E_];
__device__ __align__(16) float g_ea[B_*E_*4];
__device__ __align__(16) int   g_indeg[B_*S_];
__device__ __align__(16) int   g_cursor[B_*S_];
__device__ __align__(16) int   g_off[B_*(S_+1)];
__device__ __align__(16) int   g_list[B_*E_];
__device__ __align__(16) float g_P[(size_t)NROW*H_];       // P part (fp32, read once/node)
__device__ __align__(16) bf    g_Qbf[(size_t)NROW*H_];     // Q part (bf16, gathered deg x)
__device__ __align__(16) float g_h[(size_t)NROW*H_];
__device__ __align__(16) bf    g_hbf[(size_t)NROW*H_];
__device__ __align__(16) bf    g_abf[(size_t)NROW*H_];     // aggregated gelu sums
__device__ __align__(16) bf    g_hh[(size_t)NROW*H_];
__device__ __align__(16) bf    g_t[(size_t)NROW*H_];
__device__ __align__(16) bf    g_w2p[(size_t)11*H_*H_];
__device__ __align__(16) bf    g_wcp[(size_t)9*H_*384];

__device__ __forceinline__ float bf2f(bf x){ return __bfloat162float(x); }
__device__ __forceinline__ float LD(const void* p, long i){
  return g_isbf16 ? __bfloat162float(((const bf*)p)[i]) : ((const float*)p)[i];
}
__device__ __forceinline__ float gelu_f(float x){ return 0.5f*x*(1.0f + erff(x*0.70710678118654752f)); }
__device__ __forceinline__ ull shfl_xor_u64(ull v, int m){
  unsigned lo = (unsigned)v, hi = (unsigned)(v >> 32);
  lo = __shfl_xor(lo, m, 64); hi = __shfl_xor(hi, m, 64);
  return ((ull)hi << 32) | lo;
}

// ---------------- input dtype detect ----------------
__global__ void k_viol(const void* a, const void* b, const void* c){
  int t = threadIdx.x;
  const bf* pa = (const bf*)a; const bf* pb = (const bf*)b; const bf* pc = (const bf*)c;
  int bad = 0;
  #pragma unroll
  for (int s = 0; s < 2; ++s){
    float va = __bfloat162float(pa[t + s*256]);
    float vb = __bfloat162float(pb[t + s*256]);
    float vc = __bfloat162float(pc[t + s*256]);
    if (!(fabsf(va) <= 1000.f)) bad = 1;
    if (!(fabsf(vb) <= 1000.f)) bad = 1;
    if (!(fabsf(vc) <= 1000.f)) bad = 1;
  }
  if (threadIdx.x == 0) g_viol = 0;
  __syncthreads();
  if (bad) atomicOr(&g_viol, 1);
  __syncthreads();
  if (threadIdx.x == 0) g_isbf16 = (g_viol == 0) ? 1 : 0;
}

__global__ void k_zero(){
  int tid = blockIdx.x*256 + threadIdx.x;
  if (tid < B_*S_){ g_indeg[tid]=0; g_cursor[tid]=0; }
  if (tid < B_*2) g_accum[tid]=0.f;
}

// ---------------- var_pp, np pairwise-8 semantics ----------------
__global__ void k_var(const void* __restrict__ vel){
  int b = blockIdx.y;
  int n = blockIdx.x*256 + threadIdx.x;
  float v = 0.f;
  #pragma unroll
  for (int c = 0; c < 3; ++c){
    float x[8];
    #pragma unroll
    for (int t = 0; t < 8; ++t)
      x[t] = LD(vel, ((long)(b*T_+t)*NN_ + n)*3 + c);
    float m = __fadd_rn(__fadd_rn(__fadd_rn(x[0],x[1]), __fadd_rn(x[2],x[3])),
                        __fadd_rn(__fadd_rn(x[4],x[5]), __fadd_rn(x[6],x[7]))) / 8.0f;
    float d[8];
    #pragma unroll
    for (int t = 0; t < 8; ++t){ float dd = __fadd_rn(x[t], -m); d[t] = __fmul_rn(dd,dd); }
    float sv = __fadd_rn(__fadd_rn(__fadd_rn(d[0],d[1]), __fadd_rn(d[2],d[3])),
                         __fadd_rn(__fadd_rn(d[4],d[5]), __fadd_rn(d[6],d[7])));
    v = __fadd_rn(v, sv / 7.0f);
  }
  g_var[b*NN_ + n] = v;
  float s1 = v, s2 = v*v;
  #pragma unroll
  for (int o = 32; o; o >>= 1){ s1 += __shfl_xor(s1,o,64); s2 += __shfl_xor(s2,o,64); }
  __shared__ float r1[4], r2[4];
  int lane = threadIdx.x & 63, wid = threadIdx.x >> 6;
  if (!lane){ r1[wid]=s1; r2[wid]=s2; }
  __syncthreads();
  if (threadIdx.x == 0){
    atomicAdd(&g_accum[b*2+0], r1[0]+r1[1]+r1[2]+r1[3]);
    atomicAdd(&g_accum[b*2+1], r2[0]+r2[1]+r2[2]+r2[3]);
  }
}

__global__ void k_soft(const void* __restrict__ air){
  int b = blockIdx.y;
  int n = blockIdx.x*256 + threadIdx.x;
  float S1 = g_accum[b*2], S2 = g_accum[b*2+1];
  float mean = S1*(1.f/NN_);
  float sd = sqrtf(fmaxf((S2 - S1*S1*(1.f/NN_))*(1.f/(NN_-1)), 0.f));
  float v = g_var[b*NN_+n];
  float z = (v-mean)/(sd+1e-8f);
  float sig = 1.f/(1.f+expf(-SHARP_*z));
  g_soft[b*NN_+n] = sig*(1.f - LD(air, b*NN_+n));
}

// ---------------- stable rank-based top-S: one wave per node ----------------
__global__ __launch_bounds__(256) void k_rank(){
  int b = blockIdx.y;
  int i = blockIdx.x*4 + (threadIdx.x >> 6);
  int lane = threadIdx.x & 63;
  float vi = g_var[b*NN_+i];
  int rank = 0;
  for (int j = lane; j < NN_; j += 64){
    float vj = g_var[b*NN_+j];
    rank += ((vj > vi) || (vj == vi && j < i)) ? 1 : 0;
  }
  #pragma unroll
  for (int o = 32; o; o >>= 1) rank += __shfl_xor(rank, o, 64);
  if (lane == 0 && rank < S_) g_topidx[b*S_ + rank] = i;
}

__global__ void k_gather(const void* __restrict__ pos, const void* __restrict__ ub,
                         const void* __restrict__ vel){
  int gi = blockIdx.x*256 + threadIdx.x;
  if (gi >= B_*S_) return;
  int b = gi / S_, s = gi - b*S_;
  int node = g_topidx[gi];
  float px = LD(pos, ((long)b*NN_+node)*3+0);
  float py = LD(pos, ((long)b*NN_+node)*3+1);
  float pz = LD(pos, ((long)b*NN_+node)*3+2);
  g_possel[gi*3+0]=px; g_possel[gi*3+1]=py; g_possel[gi*3+2]=pz;
  g_masksel[gi] = g_soft[b*NN_+node];
  float vf = g_var[b*NN_+node];
  float vl0 = LD(vel, ((long)(b*T_+7)*NN_+node)*3+0);
  float vl1 = LD(vel, ((long)(b*T_+7)*NN_+node)*3+1);
  float vl2 = LD(vel, ((long)(b*T_+7)*NN_+node)*3+2);
  for (int k = 0; k < K_; ++k){
    long row = (long)(b*K_+k)*S_ + s;
    float* x = g_x0 + row*10;
    x[0]=LD(ub, ((long)(b*K_+k)*NN_+node)*3+0);
    x[1]=LD(ub, ((long)(b*K_+k)*NN_+node)*3+1);
    x[2]=LD(ub, ((long)(b*K_+k)*NN_+node)*3+2);
    x[3]=vl0; x[4]=vl1; x[5]=vl2;
    x[6]=px;  x[7]=py;  x[8]=pz;
    x[9]=vf;
  }
}

// ---------------- KNN: one wave per query node ----------------
__global__ __launch_bounds__(256) void k_knn(){
  __shared__ float px[S_], py[S_], pz[S_];
  int b = blockIdx.y;
  int j = blockIdx.x*4 + (threadIdx.x >> 6);
  int lane = threadIdx.x & 63;
  for (int t = threadIdx.x; t < S_; t += 256){
    px[t] = g_possel[(b*S_+t)*3+0];
    py[t] = g_possel[(b*S_+t)*3+1];
    pz[t] = g_possel[(b*S_+t)*3+2];
  }
  __syncthreads();
  if (j >= S_) return;
  float xj=px[j], yj=py[j], zj=pz[j];
  float dist[KK_]; int id[KK_];
  #pragma unroll
  for (int t = 0; t < KK_; ++t){ dist[t]=3.0e38f; id[t]=0x7fffffff; }
  for (int c = lane; c < S_; c += 64){
    if (c == j) continue;
    float dx=__fadd_rn(px[c],-xj), dy=__fadd_rn(py[c],-yj), dz=__fadd_rn(pz[c],-zj);
    float d2 = __fadd_rn(__fadd_rn(__fmul_rn(dx,dx), __fmul_rn(dy,dy)), __fmul_rn(dz,dz));
    if (d2 < dist[KK_-1]){
      int p = 0;
      #pragma unroll
      for (int q = 0; q < KK_; ++q) p += (dist[q] <= d2) ? 1 : 0;
      #pragma unroll
      for (int q = KK_-1; q >= 1; --q){
        bool mv = (q > p);
        dist[q] = mv ? dist[q-1] : dist[q];
        id[q]   = mv ? id[q-1]   : id[q];
      }
      #pragma unroll
      for (int q = 0; q < KK_; ++q){ if (q == p){ dist[q] = d2; id[q] = c; } }
    }
  }
  ull mykey = 0;
  #pragma unroll
  for (int t = 0; t < KK_; ++t){
    ull k = (((ull)__float_as_uint(dist[0])) << 32) | (unsigned)id[0];
    ull m = k;
    #pragma unroll
    for (int o = 32; o; o >>= 1){ ull other = shfl_xor_u64(m, o); m = (other < m) ? other : m; }
    if (k == m){
      #pragma unroll
      for (int q = 0; q < KK_-1; ++q){ dist[q]=dist[q+1]; id[q]=id[q+1]; }
      dist[KK_-1] = 3.0e38f; id[KK_-1] = 0x7fffffff;
    }
    if (lane == t) mykey = m;
  }
  if (lane < KK_){
    int i = (int)(mykey & 0xffffffffu);
    g_knn[(b*S_+j)*KK_ + lane] = i;
    float rx = __fadd_rn(px[i],-xj), ry = __fadd_rn(py[i],-yj), rz = __fadd_rn(pz[i],-zj);
    float dd = sqrtf(__fadd_rn(__fadd_rn(__fmul_rn(rx,rx), __fmul_rn(ry,ry)), __fmul_rn(rz,rz)));
    float* o = g_ea + ((long)b*E_ + j*KK_ + lane)*4;
    o[0]=rx; o[1]=ry; o[2]=rz; o[3]=dd;
    atomicAdd(&g_indeg[b*S_+i], 1);
  }
}

__global__ void k_scan(){
  __shared__ int sA[2048], sB[2048];
  int b = blockIdx.x, tid = threadIdx.x;   // 1024
  for (int i = tid; i < 2048; i += 1024) sA[i] = (i < S_) ? g_indeg[b*S_+i] : 0;
  __syncthreads();
  int *src = sA, *dst = sB;
  for (int d = 1; d < 2048; d <<= 1){
    for (int i = tid; i < 2048; i += 1024) dst[i] = src[i] + (i >= d ? src[i-d] : 0);
    __syncthreads();
    int* t2 = src; src = dst; dst = t2;
  }
  if (tid == 0) g_off[b*(S_+1)] = 0;
  for (int i = tid; i < S_; i += 1024) g_off[b*(S_+1)+i+1] = src[i];
}

__global__ void k_fill(){
  int idx = blockIdx.x*256 + threadIdx.x;
  if (idx >= B_*E_) return;
  int b = idx / E_, e = idx - b*E_;
  int i = g_knn[idx];
  int slot = atomicAdd(&g_cursor[b*S_+i], 1);
  g_list[b*E_ + g_off[b*(S_+1)+i] + slot] = e;
}

// ---------------- weight packing ----------------
__global__ void k_pack_w2(const void* __restrict__ c0w2, const void* __restrict__ cw2,
                          const void* __restrict__ hw1){
  int gi = blockIdx.x*256 + threadIdx.x;
  if (gi >= 11*H_*H_) return;
  int mat = gi / (H_*H_), r = gi - mat*(H_*H_);
  int k = r / H_, n = r - (r/H_)*H_;
  float v;
  if (mat == 0)      v = LD(c0w2, (long)k*H_ + n);
  else if (mat <= 9) v = LD(cw2, (long)(mat-1)*H_*H_ + (long)k*H_ + n);
  else               v = LD(hw1, (long)k*H_ + n);
  int t = k>>5, q = (k>>3)&3, jj = k&7;
  g_w2p[(size_t)mat*H_*H_ + (((t*4+q)*H_ + n)*8 + jj)] = __float2bfloat16(v);
}

__global__ void k_pack_wc(const void* __restrict__ cw1){
  int gi = blockIdx.x*256 + threadIdx.x;
  if (gi >= 9*H_*384) return;
  int l = gi / (H_*384), r = gi - l*(H_*384);
  int k = r / 384, n = r - (r/384)*384;
  long base = (long)l*388*H_;
  float v;
  if (n < H_) v = LD(cw1, base + (long)k*H_ + n) - LD(cw1, base + (long)(H_+k)*H_ + n);
  else        v = LD(cw1, base + (long)(H_+k)*H_ + (n-H_));
  int t = k>>5, q = (k>>3)&3, jj = k&7;
  g_wcp[(size_t)l*(H_*384) + (((t*4+q)*384 + n)*8 + jj)] = __float2bfloat16(v);
}

// ---------------- conv0 node projection (K=10) ----------------
__global__ void k_proj0(const void* __restrict__ w1){
  int gi = blockIdx.x*256 + threadIdx.x;
  if (gi >= NROW*384) return;
  int row = gi / 384, n = gi - (gi/384)*384;
  const float* x = g_x0 + (size_t)row*10;
  float acc = 0.f;
  if (n < H_){
    #pragma unroll
    for (int f = 0; f < 10; ++f) acc += x[f] * (LD(w1, f*H_+n) - LD(w1, (10+f)*H_+n));
    g_P[(size_t)row*H_ + n] = acc;
  } else {
    int hc = n - H_;
    #pragma unroll
    for (int f = 0; f < 10; ++f) acc += x[f] * LD(w1, (10+f)*H_+hc);
    g_Qbf[(size_t)row*H_ + hc] = __float2bfloat16(acc);
  }
}

// ---------------- MFMA GEMM MODE 0: PQ projection, N=384 ----------------
__global__ __launch_bounds__(256) void k_gemmPQ(int bOff, int M){
  const bf* A  = g_hbf;
  const bf* Bp = g_wcp + bOff;
  int wave = threadIdx.x >> 6, lane = threadIdx.x & 63;
  int q = lane >> 4, l16 = lane & 15;
  long rowBase = (long)blockIdx.x * 32;
  f32x4 acc[2][6];
  #pragma unroll
  for (int rt = 0; rt < 2; ++rt)
    #pragma unroll
    for (int ct = 0; ct < 6; ++ct) acc[rt][ct] = (f32x4){0.f,0.f,0.f,0.f};
  #pragma unroll
  for (int t = 0; t < 6; ++t){
    int kof = t*32 + q*8;
    bf16x8 af[2], bfr[6];
    #pragma unroll
    for (int rt = 0; rt < 2; ++rt){
      long r = rowBase + rt*16 + l16;
      if (r >= M) r = M-1;
      af[rt] = *reinterpret_cast<const bf16x8*>(A + r*192 + kof);
    }
    #pragma unroll
    for (int ct = 0; ct < 6; ++ct){
      int n = wave*96 + ct*16 + l16;
      bfr[ct] = *reinterpret_cast<const bf16x8*>(Bp + (((t*4+q)*384 + n)*8));
    }
    #pragma unroll
    for (int rt = 0; rt < 2; ++rt)
      #pragma unroll
      for (int ct = 0; ct < 6; ++ct)
        acc[rt][ct] = __builtin_amdgcn_mfma_f32_16x16x32_bf16(af[rt], bfr[ct], acc[rt][ct], 0,0,0);
  }
  #pragma unroll
  for (int rt = 0; rt < 2; ++rt){
    #pragma unroll
    for (int ct = 0; ct < 6; ++ct){
      int col = wave*96 + ct*16 + l16;
      #pragma unroll
      for (int r = 0; r < 4; ++r){
        long row = rowBase + rt*16 + q*4 + r;
        if (row < M){
          float v = acc[rt][ct][r];
          if (col < 192) g_P[row*192 + col] = v;
          else           g_Qbf[row*192 + (col-192)] = __float2bfloat16(v);
        }
      }
    }
  }
}

// ---------------- fused MFMA GEMM (m2) + deg*b2 + LayerNorm + residual ----------------
template<int RES>
__global__ __launch_bounds__(256) void k_gemmln(const void* __restrict__ biasB, long biasO,
                                                const void* __restrict__ gB, long gO,
                                                const void* __restrict__ beB, long beO,
                                                int bOff, int M){
  const bf* A  = g_abf;
  const bf* Bp = g_w2p + bOff;
  int wave = threadIdx.x >> 6, lane = threadIdx.x & 63;
  int q = lane >> 4, l16 = lane & 15;
  long rowBase = (long)blockIdx.x * 32;
  f32x4 acc[2][3];
  #pragma unroll
  for (int rt = 0; rt < 2; ++rt)
    #pragma unroll
    for (int ct = 0; ct < 3; ++ct) acc[rt][ct] = (f32x4){0.f,0.f,0.f,0.f};
  #pragma unroll
  for (int t = 0; t < 6; ++t){
    int kof = t*32 + q*8;
    bf16x8 af[2], bfr[3];
    #pragma unroll
    for (int rt = 0; rt < 2; ++rt){
      long r = rowBase + rt*16 + l16;
      if (r >= M) r = M-1;
      af[rt] = *reinterpret_cast<const bf16x8*>(A + r*192 + kof);
    }
    #pragma unroll
    for (int ct = 0; ct < 3; ++ct){
      int n = wave*48 + ct*16 + l16;
      bfr[ct] = *reinterpret_cast<const bf16x8*>(Bp + (((t*4+q)*192 + n)*8));
    }
    #pragma unroll
    for (int rt = 0; rt < 2; ++rt)
      #pragma unroll
      for (int ct = 0; ct < 3; ++ct)
        acc[rt][ct] = __builtin_amdgcn_mfma_f32_16x16x32_bf16(af[rt], bfr[ct], acc[rt][ct], 0,0,0);
  }
  __shared__ float tile[32][200];
  __shared__ float srow[32], rrow[32];
  #pragma unroll
  for (int rt = 0; rt < 2; ++rt){
    #pragma unroll
    for (int ct = 0; ct < 3; ++ct){
      int col = wave*48 + ct*16 + l16;
      float bb = LD(biasB, biasO + col);
      #pragma unroll
      for (int r = 0; r < 4; ++r){
        int lr = rt*16 + q*4 + r;
        long row = rowBase + lr;
        long rowc = (row < M) ? row : (M-1);
        int bk = (int)(rowc / S_); int i = (int)(rowc - (long)bk*S_); int b = bk >> 1;
        float degf = (float)(g_off[b*(S_+1)+i+1] - g_off[b*(S_+1)+i]);
        tile[lr][col] = acc[rt][ct][r] + degf*bb;
      }
    }
  }
  __syncthreads();
  {
    int lr = threadIdx.x >> 3;      // 0..31
    int k8 = threadIdx.x & 7;       // 0..7
    float s = 0.f, qq = 0.f;
    for (int c = k8; c < 192; c += 8){ float x = tile[lr][c]; s += x; qq += x*x; }
    #pragma unroll
    for (int o = 1; o < 8; o <<= 1){ s += __shfl_xor(s,o,64); qq += __shfl_xor(qq,o,64); }
    if (k8 == 0){
      float mu = s*(1.f/H_);
      float var = qq*(1.f/H_) - mu*mu;
      srow[lr] = mu;
      rrow[lr] = rsqrtf(fmaxf(var, 0.f) + 1e-5f);
    }
  }
  __syncthreads();
  #pragma unroll
  for (int rt = 0; rt < 2; ++rt){
    #pragma unroll
    for (int ct = 0; ct < 3; ++ct){
      int col = wave*48 + ct*16 + l16;
      float gg = LD(gB, gO+col), be = LD(beB, beO+col);
      #pragma unroll
      for (int r = 0; r < 4; ++r){
        int lr = rt*16 + q*4 + r;
        long row = rowBase + lr;
        if (row < M){
          float y = (tile[lr][col] - srow[lr])*rrow[lr]*gg + be;
          if (RES) y += g_h[row*192 + col];
          g_h[row*192 + col] = y;
          g_hbf[row*192 + col] = __float2bfloat16(y);
        }
      }
    }
  }
}

// ---------------- MFMA GEMM MODE 2: head t = gelu(hh@hw1+hb1) ----------------
__global__ __launch_bounds__(256) void k_gemmhead(const void* __restrict__ biasB,
                                                  int bOff, int M){
  const bf* A  = g_hh;
  const bf* Bp = g_w2p + bOff;
  int wave = threadIdx.x >> 6, lane = threadIdx.x & 63;
  int q = lane >> 4, l16 = lane & 15;
  long rowBase = (long)blockIdx.x * 32;
  f32x4 acc[2][3];
  #pragma unroll
  for (int rt = 0; rt < 2; ++rt)
    #pragma unroll
    for (int ct = 0; ct < 3; ++ct) acc[rt][ct] = (f32x4){0.f,0.f,0.f,0.f};
  #pragma unroll
  for (int t = 0; t < 6; ++t){
    int kof = t*32 + q*8;
    bf16x8 af[2], bfr[3];
    #pragma unroll
    for (int rt = 0; rt < 2; ++rt){
      long r = rowBase + rt*16 + l16;
      if (r >= M) r = M-1;
      af[rt] = *reinterpret_cast<const bf16x8*>(A + r*192 + kof);
    }
    #pragma unroll
    for (int ct = 0; ct < 3; ++ct){
      int n = wave*48 + ct*16 + l16;
      bfr[ct] = *reinterpret_cast<const bf16x8*>(Bp + (((t*4+q)*192 + n)*8));
    }
    #pragma unroll
    for (int rt = 0; rt < 2; ++rt)
      #pragma unroll
      for (int ct = 0; ct < 3; ++ct)
        acc[rt][ct] = __builtin_amdgcn_mfma_f32_16x16x32_bf16(af[rt], bfr[ct], acc[rt][ct], 0,0,0);
  }
  #pragma unroll
  for (int rt = 0; rt < 2; ++rt){
    #pragma unroll
    for (int ct = 0; ct < 3; ++ct){
      int col = wave*48 + ct*16 + l16;
      float bb = LD(biasB, col);
      #pragma unroll
      for (int r = 0; r < 4; ++r){
        long row = rowBase + rt*16 + q*4 + r;
        if (row < M) g_t[row*192 + col] = __float2bfloat16(gelu_f(acc[rt][ct][r] + bb));
      }
    }
  }
}

// ---------------- fused edge-compute + CSR aggregate (unroll x4) ----------------
__global__ __launch_bounds__(192) void k_aggedge(const void* __restrict__ w1cB, long w1cO,
                                                 const void* __restrict__ b1B, long b1O){
  int row = blockIdx.x;   // NROW
  int col = threadIdx.x;  // 192
  int bk = row / S_, i = row - bk*S_, b = bk >> 1;
  int off = g_off[b*(S_+1)+i];
  int deg = g_off[b*(S_+1)+i+1] - off;
  float w0 = LD(w1cB, w1cO+col),       w1v = LD(w1cB, w1cO+H_+col);
  float w2v = LD(w1cB, w1cO+2*H_+col), w3v = LD(w1cB, w1cO+3*H_+col);
  float base = g_P[(size_t)row*H_ + col] + LD(b1B, b1O+col);
  const int* lst = g_list + b*E_ + off;
  const bf* Q = g_Qbf + (size_t)bk*S_*H_;
  const float* EA = g_ea + (size_t)b*E_*4;
  float acc = 0.f;
  int d = 0;
  for (; d + 4 <= deg; d += 4){
    int e0 = lst[d], e1 = lst[d+1], e2 = lst[d+2], e3 = lst[d+3];
    float4 a0 = *reinterpret_cast<const float4*>(EA + (size_t)e0*4);
    float4 a1 = *reinterpret_cast<const float4*>(EA + (size_t)e1*4);
    float4 a2 = *reinterpret_cast<const float4*>(EA + (size_t)e2*4);
    float4 a3 = *reinterpret_cast<const float4*>(EA + (size_t)e3*4);
    float q0 = bf2f(Q[(size_t)(e0>>4)*H_ + col]);
    float q1 = bf2f(Q[(size_t)(e1>>4)*H_ + col]);
    float q2 = bf2f(Q[(size_t)(e2>>4)*H_ + col]);
    float q3 = bf2f(Q[(size_t)(e3>>4)*H_ + col]);
    acc += gelu_f(base + q0 + a0.x*w0 + a0.y*w1v + a0.z*w2v + a0.w*w3v);
    acc += gelu_f(base + q1 + a1.x*w0 + a1.y*w1v + a1.z*w2v + a1.w*w3v);
    acc += gelu_f(base + q2 + a2.x*w0 + a2.y*w1v + a2.z*w2v + a2.w*w3v);
    acc += gelu_f(base + q3 + a3.x*w0 + a3.y*w1v + a3.z*w2v + a3.w*w3v);
  }
  for (; d < deg; ++d){
    int e = lst[d];
    float4 a = *reinterpret_cast<const float4*>(EA + (size_t)e*4);
    float qv = bf2f(Q[(size_t)(e>>4)*H_ + col]);
    acc += gelu_f(base + qv + a.x*w0 + a.y*w1v + a.z*w2v + a.w*w3v);
  }
  g_abf[(size_t)row*H_ + col] = __float2bfloat16(acc);
}

__global__ void k_lnhead(const void* __restrict__ g, const void* __restrict__ be){
  int row = blockIdx.x;
  int col = threadIdx.x;
  float x = g_h[(size_t)row*H_ + col];
  float s = x, qq = x*x;
  #pragma unroll
  for (int o = 32; o; o >>= 1){ s += __shfl_xor(s,o,64); qq += __shfl_xor(qq,o,64); }
  __shared__ float ws[3][2];
  int wid = col >> 6, lane = col & 63;
  if (!lane){ ws[wid][0]=s; ws[wid][1]=qq; }
  __syncthreads();
  float Sm = ws[0][0]+ws[1][0]+ws[2][0];
  float Qm = ws[0][1]+ws[1][1]+ws[2][1];
  float mu = Sm*(1.f/H_);
  float var = Qm*(1.f/H_) - mu*mu;
  float rstd = rsqrtf(fmaxf(var, 0.f) + 1e-5f);
  g_hh[(size_t)row*H_ + col] = __float2bfloat16((x-mu)*rstd*LD(g,col) + LD(be,col));
}

// ---------------- output (fp32) ----------------
__global__ void k_initout(const void* __restrict__ ub, const void* __restrict__ air, float* __restrict__ out){
  int gi = blockIdx.x*256 + threadIdx.x;   // 49152
  int n = (gi/3) % NN_;
  int b = gi / (K_*NN_*C_);
  float a = 1.f - LD(air, b*NN_+n);
  out[gi] = LD(ub, gi) * a;
}

__global__ void k_headout(const void* __restrict__ w2, const void* __restrict__ b2,
                          const void* __restrict__ ub, const void* __restrict__ air,
                          float* __restrict__ out){
  int row = blockIdx.x*4 + (threadIdx.x >> 6);
  int lane = threadIdx.x & 63;
  if (row >= NROW) return;
  float t0 = bf2f(g_t[(size_t)row*H_ + lane]);
  float t1 = bf2f(g_t[(size_t)row*H_ + lane + 64]);
  float t2 = bf2f(g_t[(size_t)row*H_ + lane + 128]);
  float d[3];
  #pragma unroll
  for (int c = 0; c < 3; ++c){
    float p = t0*LD(w2,lane*3+c) + t1*LD(w2,(lane+64)*3+c) + t2*LD(w2,(lane+128)*3+c);
    #pragma unroll
    for (int o = 32; o; o >>= 1) p += __shfl_xor(p,o,64);
    d[c] = p + LD(b2,c);
  }
  if (lane == 0){
    int bk = row / S_, s = row - bk*S_, b = bk >> 1;
    float msk = g_masksel[b*S_+s];
    int node = g_topidx[b*S_+s];
    float am = 1.f - LD(air, b*NN_+node);
    #pragma unroll
    for (int c = 0; c < 3; ++c){
      long oi = ((long)bk*NN_ + node)*3 + c;
      out[oi] = (LD(ub,oi) + d[c]*msk)*am;
    }
  }
}

extern "C" void kernel_launch(void* const* d_in, const int* in_sizes, int n_in,
                              void* d_out, int out_size, void* d_ws, size_t ws_size,
                              hipStream_t stream) {
  (void)in_sizes; (void)n_in; (void)d_ws; (void)ws_size; (void)out_size;
  const void* u_base = d_in[0];
  const void* pos    = d_in[1];
  const void* vel    = d_in[2];
  const void* air    = d_in[3];
  const void* c0w1   = d_in[4];
  const void* c0b1   = d_in[5];
  const void* c0w2   = d_in[6];
  const void* c0b2   = d_in[7];
  const void* c0g    = d_in[8];
  const void* c0be   = d_in[9];
  const void* cw1    = d_in[10];
  const void* cb1    = d_in[11];
  const void* cw2    = d_in[12];
  const void* cb2    = d_in[13];
  const void* cg     = d_in[14];
  const void* cbe    = d_in[15];
  const void* hg     = d_in[16];
  const void* hbe    = d_in[17];
  const void* hw1    = d_in[18];
  const void* hb1    = d_in[19];
  const void* hw2    = d_in[20];
  const void* hb2    = d_in[21];
  float* out = (float*)d_out;

  k_viol<<<1, 256, 0, stream>>>(u_base, pos, vel);
  k_zero<<<13, 256, 0, stream>>>();
  k_var<<<dim3(16, B_), 256, 0, stream>>>(vel);
  k_soft<<<dim3(16, B_), 256, 0, stream>>>(air);
  k_rank<<<dim3(NN_/4, B_), 256, 0, stream>>>();
  k_gather<<<13, 256, 0, stream>>>(pos, u_base, vel);
  k_knn<<<dim3((S_+3)/4, B_), 256, 0, stream>>>();
  k_scan<<<B_, 1024, 0, stream>>>();
  k_fill<<<205, 256, 0, stream>>>();
  k_pack_w2<<<1584, 256, 0, stream>>>(c0w2, cw2, hw1);
  k_pack_wc<<<2592, 256, 0, stream>>>(cw1);
  k_initout<<<192, 256, 0, stream>>>(u_base, air, out);
  k_proj0<<<9828, 256, 0, stream>>>(c0w1);

  const int GN = (NROW + 31) / 32;   // 205
  for (int l = 0; l < 10; ++l){
    if (l > 0) k_gemmPQ<<<GN, 256, 0, stream>>>((l-1)*H_*384, NROW);

    long w1cO = (l == 0) ? 20L*H_ : ((long)(l-1)*388 + 384)*H_;
    const void* w1cB = (l == 0) ? c0w1 : cw1;
    long lOff = (l == 0) ? 0 : (long)(l-1)*H_;
    const void* b1B = (l == 0) ? c0b1 : cb1;
    k_aggedge<<<NROW, 192, 0, stream>>>(w1cB, w1cO, b1B, lOff);

    const void* b2B = (l == 0) ? c0b2 : cb2;
    const void* gB  = (l == 0) ? c0g  : cg;
    const void* beB = (l == 0) ? c0be : cbe;
    if (l > 0) k_gemmln<1><<<GN, 256, 0, stream>>>(b2B, lOff, gB, lOff, beB, lOff, l*H_*H_, NROW);
    else       k_gemmln<0><<<GN, 256, 0, stream>>>(b2B, lOff, gB, lOff, beB, lOff, l*H_*H_, NROW);
  }

  k_lnhead<<<NROW, 192, 0, stream>>>(hg, hbe);
  k_gemmhead<<<GN, 256, 0, stream>>>(hb1, 10*H_*H_, NROW);
  k_headout<<<NROW/4, 256, 0, stream>>>(hw2, hb2, u_base, air, out);
}